// Round 1
// baseline (32162.802 us; speedup 1.0000x reference)
//
#include <hip/hip_runtime.h>
#include <hip/hip_bf16.h>
#include <math.h>

// Problem constants
#define B_   8
#define L_   512
#define D_   1024
#define H_   16
#define DKH_ 64      // dk per head
#define FILT_ 4096
#define NLAYERS_ 6
#define ROWS_ (B_*L_)            // 4096
#define NE_   ((size_t)ROWS_*D_) // 4194304 elements per (B,L,D) tensor

// ---------------------------------------------------------------------------
// Embedding lookup: state[row,:] = emb[X[row],:]
__global__ __launch_bounds__(256) void embed_kernel(const int* __restrict__ X,
                                                    const float* __restrict__ emb,
                                                    float* __restrict__ state) {
    int row = blockIdx.x;
    int tok = X[row];
    const float4* src = (const float4*)(emb + (size_t)tok * D_);
    float4* dst = (float4*)(state + (size_t)row * D_);
    dst[threadIdx.x] = src[threadIdx.x];   // 256 * 4 floats = 1024
}

// ---------------------------------------------------------------------------
// state += TIME_SIG[l,c] + POS_SIG[t,c]
__global__ __launch_bounds__(256) void add_sig_kernel(float* __restrict__ state, int layer_t) {
    int idx = blockIdx.x * 256 + threadIdx.x;      // over 4M elements
    int c = idx & (D_ - 1);
    int l = (idx >> 10) & (L_ - 1);
    const float log_inc = 0.0180241494559220821f;  // log(10000)/511
    int j = c & 511;
    float inv = expf(-log_inc * (float)j);
    float tv, pv;
    if (c < 512) { tv = sinf((float)l * inv); pv = sinf((float)layer_t * inv); }
    else         { tv = cosf((float)l * inv); pv = cosf((float)layer_t * inv); }
    state[idx] += tv + pv;
}

// ---------------------------------------------------------------------------
// ACT halting update, one block per (b,l) row
__global__ __launch_bounds__(256) void act_kernel(const float* __restrict__ state,
                                                  const float* __restrict__ p_w,
                                                  const float* __restrict__ p_b,
                                                  float* __restrict__ hp, float* __restrict__ rem,
                                                  float* __restrict__ nup, float* __restrict__ uw) {
    int row = blockIdx.x;
    const float* x = state + (size_t)row * D_;
    float s = 0.f;
    for (int i = threadIdx.x; i < D_; i += 256) s += x[i] * p_w[i];
    __shared__ float red[256];
    red[threadIdx.x] = s; __syncthreads();
    for (int st = 128; st > 0; st >>= 1) {
        if (threadIdx.x < st) red[threadIdx.x] += red[threadIdx.x + st];
        __syncthreads();
    }
    if (threadIdx.x == 0) {
        float p = 1.f / (1.f + expf(-(red[0] + p_b[0])));
        float h = hp[row], r = rem[row], n = nup[row];
        float still = (h < 1.0f) ? 1.f : 0.f;
        float add = h + p * still;
        float nh    = (add > 0.9f) ? still : 0.f;
        float still2 = (add <= 0.9f) ? still : 0.f;
        h += p * still2;
        r += nh * (1.f - h);
        h += nh * r;
        n += still2 + nh;
        hp[row] = h; rem[row] = r; nup[row] = n;
        uw[row] = p * still2 + nh * r;
    }
}

// ---------------------------------------------------------------------------
// LayerNorm (ddof=1 std, eps added to sd), one block per row
__global__ __launch_bounds__(256) void ln_kernel(const float* __restrict__ x,
                                                 const float* __restrict__ g,
                                                 const float* __restrict__ b,
                                                 float* __restrict__ y) {
    int row = blockIdx.x;
    const float4* xr = (const float4*)(x + (size_t)row * D_);
    float4 v = xr[threadIdx.x];
    __shared__ float red[256];
    float s = v.x + v.y + v.z + v.w;
    red[threadIdx.x] = s; __syncthreads();
    for (int st = 128; st > 0; st >>= 1) { if (threadIdx.x < st) red[threadIdx.x] += red[threadIdx.x + st]; __syncthreads(); }
    float mu = red[0] * (1.f / D_);
    __syncthreads();
    float dx0 = v.x - mu, dx1 = v.y - mu, dx2 = v.z - mu, dx3 = v.w - mu;
    red[threadIdx.x] = dx0*dx0 + dx1*dx1 + dx2*dx2 + dx3*dx3; __syncthreads();
    for (int st = 128; st > 0; st >>= 1) { if (threadIdx.x < st) red[threadIdx.x] += red[threadIdx.x + st]; __syncthreads(); }
    float sd = sqrtf(red[0] * (1.f / (D_ - 1)));
    float inv = 1.f / (sd + 1e-6f);
    const float4* g4 = (const float4*)g;
    const float4* b4 = (const float4*)b;
    float4 gv = g4[threadIdx.x], bv = b4[threadIdx.x];
    float4 o;
    o.x = gv.x * dx0 * inv + bv.x;
    o.y = gv.y * dx1 * inv + bv.y;
    o.z = gv.z * dx2 * inv + bv.z;
    o.w = gv.w * dx3 * inv + bv.w;
    ((float4*)(y + (size_t)row * D_))[threadIdx.x] = o;
}

// ---------------------------------------------------------------------------
// Tiled fp32 GEMM.  C[M,N] (+)= relu?(scale*A@B + bias).
// TAPS==3: A is im2col view of a (B,L,Din) tensor with kernel-3 / pad-1 conv,
//          Din = 1<<DIN_SHIFT, K = 3*Din.
template<int TAPS, int DIN_SHIFT>
__global__ __launch_bounds__(256) void gemm_kernel(const float* __restrict__ A,
                                                   const float* __restrict__ Bw,
                                                   float* __restrict__ C,
                                                   const float* __restrict__ bias,
                                                   int M, int K, int N,
                                                   float scale, int do_relu, int do_acc) {
    __shared__ float As[16][68];
    __shared__ float Bs[16][68];
    int tid = threadIdx.x;
    int tx = tid & 15, ty = tid >> 4;
    int m0 = blockIdx.y * 64;
    int n0 = blockIdx.x * 64;
    float acc[4][4];
#pragma unroll
    for (int i = 0; i < 4; ++i)
#pragma unroll
        for (int j = 0; j < 4; ++j) acc[i][j] = 0.f;

    for (int k0 = 0; k0 < K; k0 += 16) {
#pragma unroll
        for (int i = 0; i < 4; ++i) {          // B tile: 16x64
            int idx = tid + i * 256;
            int kk = idx >> 6, nn = idx & 63;
            Bs[kk][nn] = Bw[(size_t)(k0 + kk) * N + n0 + nn];
        }
#pragma unroll
        for (int i = 0; i < 4; ++i) {          // A tile: 16(k) x 64(m)
            int idx = tid + i * 256;
            int kk = idx & 15, mm = idx >> 4;
            int row = m0 + mm, col = k0 + kk;
            float val;
            if (TAPS == 1) {
                val = A[(size_t)row * K + col];
            } else {
                int tap = col >> DIN_SHIFT;
                int c = col & ((1 << DIN_SHIFT) - 1);
                int bb = row >> 9, t = row & (L_ - 1);
                int ts = t + tap - 1;
                val = (ts >= 0 && ts < L_)
                        ? A[((size_t)((bb << 9) + ts) << DIN_SHIFT) + c] : 0.f;
            }
            As[kk][mm] = val;
        }
        __syncthreads();
#pragma unroll
        for (int kk = 0; kk < 16; ++kk) {
            float4 av = *(const float4*)&As[kk][ty * 4];
            float4 bv = *(const float4*)&Bs[kk][tx * 4];
            float a[4] = {av.x, av.y, av.z, av.w};
            float bb2[4] = {bv.x, bv.y, bv.z, bv.w};
#pragma unroll
            for (int i = 0; i < 4; ++i)
#pragma unroll
                for (int j = 0; j < 4; ++j) acc[i][j] += a[i] * bb2[j];
        }
        __syncthreads();
    }
#pragma unroll
    for (int i = 0; i < 4; ++i) {
        int row = m0 + ty * 4 + i;
#pragma unroll
        for (int j = 0; j < 4; ++j) {
            int col = n0 + tx * 4 + j;
            float v = acc[i][j] * scale;
            if (bias) v += bias[col];
            if (do_relu) v = fmaxf(v, 0.f);
            size_t off = (size_t)row * N + col;
            if (do_acc) v += C[off];
            C[off] = v;
        }
    }
}

// ---------------------------------------------------------------------------
// Attention: one block per (qi, h, b).  Full-row softmax over L=512 keys.
__global__ __launch_bounds__(256) void attn_kernel(const float* __restrict__ q,
                                                   const float* __restrict__ k,
                                                   const float* __restrict__ v,
                                                   float* __restrict__ ctx) {
    int qi = blockIdx.x, h = blockIdx.y, b = blockIdx.z;
    __shared__ float qs[64];
    __shared__ float sc[512];
    __shared__ float red[256];
    __shared__ float part[4][64];
    int tid = threadIdx.x;
    size_t hoff = (size_t)h * DKH_;
    size_t rowbase = (size_t)(b * L_ + qi) * D_;
    if (tid < 64) qs[tid] = q[rowbase + hoff + tid];
    __syncthreads();
    for (int kk = tid; kk < L_; kk += 256) {
        const float* kr = k + (size_t)(b * L_ + kk) * D_ + hoff;
        float s = 0.f;
#pragma unroll
        for (int d = 0; d < 64; d += 4) {
            float4 kv = *(const float4*)(kr + d);
            s += qs[d] * kv.x + qs[d + 1] * kv.y + qs[d + 2] * kv.z + qs[d + 3] * kv.w;
        }
        sc[kk] = s;
    }
    __syncthreads();
    // max
    float m = fmaxf(sc[tid], sc[tid + 256]);
    red[tid] = m; __syncthreads();
    for (int st = 128; st > 0; st >>= 1) { if (tid < st) red[tid] = fmaxf(red[tid], red[tid + st]); __syncthreads(); }
    float mx = red[0];
    __syncthreads();
    float e0 = expf(sc[tid] - mx), e1 = expf(sc[tid + 256] - mx);
    sc[tid] = e0; sc[tid + 256] = e1;
    red[tid] = e0 + e1; __syncthreads();
    for (int st = 128; st > 0; st >>= 1) { if (tid < st) red[tid] += red[tid + st]; __syncthreads(); }
    float denom = red[0];
    __syncthreads();
    int d = tid & 63, grp = tid >> 6;
    float acc = 0.f;
    for (int kk = grp * 128; kk < grp * 128 + 128; ++kk)
        acc += sc[kk] * v[(size_t)(b * L_ + kk) * D_ + hoff + d];
    part[grp][d] = acc;
    __syncthreads();
    if (tid < 64) {
        float r = (part[0][tid] + part[1][tid] + part[2][tid] + part[3][tid]) / denom;
        ctx[rowbase + hoff + tid] = r;
    }
}

// ---------------------------------------------------------------------------
// prev = state*uw + prev*(1-uw)
__global__ __launch_bounds__(256) void prev_kernel(const float* __restrict__ state,
                                                   float* __restrict__ prev,
                                                   const float* __restrict__ uw) {
    int idx = blockIdx.x * 256 + threadIdx.x;
    int row = idx >> 10;
    float u = uw[row];
    prev[idx] = state[idx] * u + prev[idx] * (1.f - u);
}

// ---------------------------------------------------------------------------
// meanbuf[b,d] = mean over L of prev
__global__ __launch_bounds__(256) void mean_kernel(const float* __restrict__ prev,
                                                   float* __restrict__ meanbuf) {
    int idx = blockIdx.x * 256 + threadIdx.x;  // 8192
    int b = idx >> 10, d = idx & (D_ - 1);
    float s = 0.f;
    for (int l = 0; l < L_; ++l) s += prev[((size_t)(b * L_ + l) << 10) + d];
    meanbuf[idx] = s * (1.f / L_);
}

// ---------------------------------------------------------------------------
// a_hat, softmax, copy rem/nup to output
__global__ __launch_bounds__(256) void final_kernel(const float* __restrict__ meanbuf,
                                                    const float* __restrict__ W_out,
                                                    const float* __restrict__ b_out,
                                                    const float* __restrict__ rem,
                                                    const float* __restrict__ nup,
                                                    float* __restrict__ out) {
    int tid = threadIdx.x;
    int grp = tid >> 3;      // 32 groups = (b,j)
    int lane = tid & 7;
    int b = grp >> 2, j = grp & 3;
    float s = 0.f;
    for (int d2 = lane; d2 < D_; d2 += 8) s += meanbuf[b * D_ + d2] * W_out[d2 * 4 + j];
    for (int st = 4; st >= 1; st >>= 1) s += __shfl_down(s, st, 8);
    __shared__ float ah[32];
    if (lane == 0) ah[grp] = s + b_out[j];
    __syncthreads();
    if (tid < 8) {
        float a0 = ah[tid * 4 + 0], a1 = ah[tid * 4 + 1], a2 = ah[tid * 4 + 2], a3 = ah[tid * 4 + 3];
        out[tid * 4 + 0] = a0; out[tid * 4 + 1] = a1; out[tid * 4 + 2] = a2; out[tid * 4 + 3] = a3;
        float mx = fmaxf(fmaxf(a0, a1), fmaxf(a2, a3));
        float e0 = expf(a0 - mx), e1 = expf(a1 - mx), e2 = expf(a2 - mx), e3 = expf(a3 - mx);
        float sm = e0 + e1 + e2 + e3;
        out[32 + tid * 4 + 0] = e0 / sm; out[32 + tid * 4 + 1] = e1 / sm;
        out[32 + tid * 4 + 2] = e2 / sm; out[32 + tid * 4 + 3] = e3 / sm;
    }
    for (int i = tid; i < ROWS_; i += 256) {
        out[64 + i] = rem[i];
        out[64 + ROWS_ + i] = nup[i];
    }
}

// ---------------------------------------------------------------------------
extern "C" void kernel_launch(void* const* d_in, const int* in_sizes, int n_in,
                              void* d_out, int out_size, void* d_ws, size_t ws_size,
                              hipStream_t stream) {
    const int*   X     = (const int*)  d_in[0];
    const float* emb   = (const float*)d_in[1];
    const float* p_w   = (const float*)d_in[2];
    const float* p_b   = (const float*)d_in[3];
    const float* Wq    = (const float*)d_in[4];
    const float* Wk    = (const float*)d_in[5];
    const float* Wv    = (const float*)d_in[6];
    const float* Wo    = (const float*)d_in[7];
    const float* ln1_g = (const float*)d_in[8];
    const float* ln1_b = (const float*)d_in[9];
    const float* ln2_g = (const float*)d_in[10];
    const float* ln2_b = (const float*)d_in[11];
    const float* K1    = (const float*)d_in[12];
    const float* c1_b  = (const float*)d_in[13];
    const float* K2    = (const float*)d_in[14];
    const float* c2_b  = (const float*)d_in[15];
    const float* W_out = (const float*)d_in[16];
    const float* b_out = (const float*)d_in[17];

    float* ws    = (float*)d_ws;
    float* state = ws;
    float* prev  = state + NE_;
    float* xn    = prev + NE_;
    float* S     = xn + NE_;            // 4*NE_ scratch: q|k|v|ctx, aliased by h
    float* qb    = S;
    float* kb    = S + NE_;
    float* vb    = S + 2 * NE_;
    float* ctx   = S + 3 * NE_;
    float* hb    = S;                   // h (4096x4096) aliases q/k/v/ctx
    float* small = S + 4 * NE_;
    float* hp  = small;
    float* rem = small + ROWS_;
    float* nup = small + 2 * ROWS_;
    float* uw  = small + 3 * ROWS_;
    float* meanbuf = small + 4 * ROWS_; // 8192

    hipMemsetAsync(prev, 0, NE_ * sizeof(float), stream);
    hipMemsetAsync(hp, 0, 3 * ROWS_ * sizeof(float), stream);

    embed_kernel<<<ROWS_, 256, 0, stream>>>(X, emb, state);

    for (int t = 0; t < NLAYERS_; ++t) {
        add_sig_kernel<<<NE_ / 256, 256, 0, stream>>>(state, t);
        act_kernel<<<ROWS_, 256, 0, stream>>>(state, p_w, p_b, hp, rem, nup, uw);
        ln_kernel<<<ROWS_, 256, 0, stream>>>(state, ln1_g, ln1_b, xn);

        dim3 g1(D_ / 64, ROWS_ / 64);   // (16, 64)
        gemm_kernel<1, 0><<<g1, 256, 0, stream>>>(xn, Wq, qb, nullptr, ROWS_, D_, D_, 0.125f, 0, 0);
        gemm_kernel<1, 0><<<g1, 256, 0, stream>>>(xn, Wk, kb, nullptr, ROWS_, D_, D_, 1.f, 0, 0);
        gemm_kernel<1, 0><<<g1, 256, 0, stream>>>(xn, Wv, vb, nullptr, ROWS_, D_, D_, 1.f, 0, 0);

        attn_kernel<<<dim3(L_, H_, B_), 256, 0, stream>>>(qb, kb, vb, ctx);

        gemm_kernel<1, 0><<<g1, 256, 0, stream>>>(ctx, Wo, state, nullptr, ROWS_, D_, D_, 1.f, 0, 1);

        ln_kernel<<<ROWS_, 256, 0, stream>>>(state, ln2_g, ln2_b, xn);

        dim3 gc1(FILT_ / 64, ROWS_ / 64);  // (64, 64)
        gemm_kernel<3, 10><<<gc1, 256, 0, stream>>>(xn, K1, hb, c1_b, ROWS_, 3 * D_, FILT_, 1.f, 1, 0);

        dim3 gc2(D_ / 64, ROWS_ / 64);     // (16, 64)
        gemm_kernel<3, 12><<<gc2, 256, 0, stream>>>(hb, K2, state, c2_b, ROWS_, 3 * FILT_, D_, 1.f, 0, 1);

        prev_kernel<<<NE_ / 256, 256, 0, stream>>>(state, prev, uw);
    }

    mean_kernel<<<(B_ * D_) / 256, 256, 0, stream>>>(prev, meanbuf);
    final_kernel<<<1, 256, 0, stream>>>(meanbuf, W_out, b_out, rem, nup, (float*)d_out);
}

// Round 3
// 14073.305 us; speedup vs baseline: 2.2854x; 2.2854x over previous
//
#include <hip/hip_runtime.h>
#include <math.h>

// Problem constants
#define B_   8
#define L_   512
#define LP_  514                 // padded rows per batch (halo row each side)
#define D_   1024
#define H_   16
#define DKH_ 64
#define FILT_ 4096
#define NLAYERS_ 6
#define ROWS_ (B_*L_)            // 4096
#define NE_   ((size_t)ROWS_*D_) // 4194304 elems per (B,L,D) tensor

typedef unsigned short ushort_t;
typedef unsigned int uint_t;
using short8 = __attribute__((ext_vector_type(8))) short;
using f32x4  = __attribute__((ext_vector_type(4))) float;

typedef const __attribute__((address_space(1))) void* gas_ptr;
typedef __attribute__((address_space(3))) void* las_ptr;
#define GLOAD_LDS16(g, s) __builtin_amdgcn_global_load_lds((gas_ptr)(g), (las_ptr)(s), 16, 0, 0)

__device__ __forceinline__ float bf2f(ushort_t h) { return __uint_as_float((uint_t)h << 16); }
__device__ __forceinline__ ushort_t f2bf(float f) {
    uint_t u = __float_as_uint(f);
    u = (u + 0x7FFFu + ((u >> 16) & 1u)) >> 16;   // RNE
    return (ushort_t)u;
}

// ---------------------------------------------------------------------------
__global__ __launch_bounds__(256) void embed_kernel(const int* __restrict__ X,
                                                    const float* __restrict__ emb,
                                                    float* __restrict__ state) {
    int row = blockIdx.x;
    int tok = X[row];
    const float4* src = (const float4*)(emb + (size_t)tok * D_);
    float4* dst = (float4*)(state + (size_t)row * D_);
    dst[threadIdx.x] = src[threadIdx.x];
}

// ---------------------------------------------------------------------------
__global__ __launch_bounds__(256) void add_sig_kernel(float* __restrict__ state, int layer_t) {
    int idx = blockIdx.x * 256 + threadIdx.x;
    int c = idx & (D_ - 1);
    int l = (idx >> 10) & (L_ - 1);
    const float log_inc = 0.0180241494559220821f;  // log(10000)/511
    int j = c & 511;
    float inv = expf(-log_inc * (float)j);
    float tv, pv;
    if (c < 512) { tv = sinf((float)l * inv); pv = sinf((float)layer_t * inv); }
    else         { tv = cosf((float)l * inv); pv = cosf((float)layer_t * inv); }
    state[idx] += tv + pv;
}

// ---------------------------------------------------------------------------
__global__ __launch_bounds__(256) void act_kernel(const float* __restrict__ state,
                                                  const float* __restrict__ p_w,
                                                  const float* __restrict__ p_b,
                                                  float* __restrict__ hp, float* __restrict__ rem,
                                                  float* __restrict__ nup, float* __restrict__ uw) {
    int row = blockIdx.x;
    const float* x = state + (size_t)row * D_;
    float s = 0.f;
    for (int i = threadIdx.x; i < D_; i += 256) s += x[i] * p_w[i];
    __shared__ float red[256];
    red[threadIdx.x] = s; __syncthreads();
    for (int st = 128; st > 0; st >>= 1) {
        if (threadIdx.x < st) red[threadIdx.x] += red[threadIdx.x + st];
        __syncthreads();
    }
    if (threadIdx.x == 0) {
        float p = 1.f / (1.f + expf(-(red[0] + p_b[0])));
        float h = hp[row], r = rem[row], n = nup[row];
        float still = (h < 1.0f) ? 1.f : 0.f;
        float add = h + p * still;
        float nh     = (add > 0.9f) ? still : 0.f;
        float still2 = (add <= 0.9f) ? still : 0.f;
        h += p * still2;
        r += nh * (1.f - h);
        h += nh * r;
        n += still2 + nh;
        hp[row] = h; rem[row] = r; nup[row] = n;
        uw[row] = p * still2 + nh * r;
    }
}

// ---------------------------------------------------------------------------
// LayerNorm (ddof=1), fp32 in, split bf16 hi/lo out.  OUT_PAD: padded layout.
template<int OUT_PAD>
__global__ __launch_bounds__(256) void ln_kernel(const float* __restrict__ x,
                                                 const float* __restrict__ g,
                                                 const float* __restrict__ b,
                                                 ushort_t* __restrict__ yh,
                                                 ushort_t* __restrict__ yl) {
    int row = blockIdx.x;
    const float4* xr = (const float4*)(x + (size_t)row * D_);
    float4 v = xr[threadIdx.x];
    __shared__ float red[256];
    float s = v.x + v.y + v.z + v.w;
    red[threadIdx.x] = s; __syncthreads();
    for (int st = 128; st > 0; st >>= 1) { if (threadIdx.x < st) red[threadIdx.x] += red[threadIdx.x + st]; __syncthreads(); }
    float mu = red[0] * (1.f / D_);
    __syncthreads();
    float dx0 = v.x - mu, dx1 = v.y - mu, dx2 = v.z - mu, dx3 = v.w - mu;
    red[threadIdx.x] = dx0*dx0 + dx1*dx1 + dx2*dx2 + dx3*dx3; __syncthreads();
    for (int st = 128; st > 0; st >>= 1) { if (threadIdx.x < st) red[threadIdx.x] += red[threadIdx.x + st]; __syncthreads(); }
    float sd = sqrtf(red[0] * (1.f / (D_ - 1)));
    float inv = 1.f / (sd + 1e-6f);
    const float4* g4 = (const float4*)g;
    const float4* b4 = (const float4*)b;
    float4 gv = g4[threadIdx.x], bv = b4[threadIdx.x];
    float o0 = gv.x * dx0 * inv + bv.x;
    float o1 = gv.y * dx1 * inv + bv.y;
    float o2 = gv.z * dx2 * inv + bv.z;
    float o3 = gv.w * dx3 * inv + bv.w;
    int orow = OUT_PAD ? ((row >> 9) * LP_ + (row & (L_ - 1)) + 1) : row;
    ushort4 oh, ol;
    oh.x = f2bf(o0); ol.x = f2bf(o0 - bf2f(oh.x));
    oh.y = f2bf(o1); ol.y = f2bf(o1 - bf2f(oh.y));
    oh.z = f2bf(o2); ol.z = f2bf(o2 - bf2f(oh.z));
    oh.w = f2bf(o3); ol.w = f2bf(o3 - bf2f(oh.w));
    ((ushort4*)(yh + (size_t)orow * D_))[threadIdx.x] = oh;
    ((ushort4*)(yl + (size_t)orow * D_))[threadIdx.x] = ol;
}

// ---------------------------------------------------------------------------
// Transpose + split: dst[nbase+c][kbase+r] = split(scale * src[r][c])
__global__ __launch_bounds__(256) void transpose_split_kernel(const float* __restrict__ src,
                                                              ushort_t* __restrict__ dhi,
                                                              ushort_t* __restrict__ dlo,
                                                              int R, int C, int dstride,
                                                              int kbase, int nbase, float scale) {
    __shared__ float tile[32][33];
    int tx = threadIdx.x & 31, ty = threadIdx.x >> 5;   // 32 x 8
    int r0 = blockIdx.y * 32, c0 = blockIdx.x * 32;
#pragma unroll
    for (int i = 0; i < 4; ++i)
        tile[ty + i * 8][tx] = src[(size_t)(r0 + ty + i * 8) * C + c0 + tx] * scale;
    __syncthreads();
#pragma unroll
    for (int i = 0; i < 4; ++i) {
        int c = c0 + ty + i * 8;
        float val = tile[tx][ty + i * 8];
        ushort_t hi = f2bf(val);
        ushort_t lo = f2bf(val - bf2f(hi));
        size_t idx = (size_t)(nbase + c) * dstride + kbase + r0 + tx;
        dhi[idx] = hi; dlo[idx] = lo;
    }
}

// ---------------------------------------------------------------------------
// Zero halo rows of all four padded activation buffers
__global__ __launch_bounds__(256) void zero_halo_kernel(ushort_t* __restrict__ xh,
                                                        ushort_t* __restrict__ xl,
                                                        ushort_t* __restrict__ hh,
                                                        ushort_t* __restrict__ hl) {
    int idx = blockIdx.x * 256 + threadIdx.x;          // 81920 total
    if (idx < 16384) {
        int b = idx >> 11, r = (idx >> 10) & 1, c = idx & 1023;
        size_t o = ((size_t)b * LP_ + r * (LP_ - 1)) * D_ + c;
        xh[o] = 0; xl[o] = 0;
    } else {
        int j = idx - 16384;
        int b = j >> 13, r = (j >> 12) & 1, c = j & 4095;
        size_t o = ((size_t)b * LP_ + r * (LP_ - 1)) * FILT_ + c;
        hh[o] = 0; hl[o] = 0;
    }
}

// ---------------------------------------------------------------------------
// bf16x3 MFMA GEMM: C = epi( A @ Bt^T ) with A ~ Ahi+Alo, B ~ Bhi+Blo.
// acc += Ahi*Bhi + Alo*Bhi + Ahi*Blo   (~fp32 precision, rel err ~2^-17)
// 128x128 tile, BK=64, 4 waves of 64x64 (4x4 MFMA 16x16x32).
// PAD: A is im2col view of padded (B, LP_, Din);  OUT_MODE: 0=f32 store,
// 1=f32 accumulate, 2=split bf16 store, 3=split bf16 store padded.
template<int PAD, int DIN_SHIFT, int OUT_MODE, int RELU, int HAS_BIAS>
__global__ __launch_bounds__(256) void mfma_gemm(const ushort_t* __restrict__ Ahi,
                                                 const ushort_t* __restrict__ Alo,
                                                 const ushort_t* __restrict__ Bhi,
                                                 const ushort_t* __restrict__ Blo,
                                                 void* __restrict__ C,
                                                 ushort_t* __restrict__ Clo,
                                                 const float* __restrict__ bias,
                                                 int M, int N, int K) {
    __shared__ __align__(16) ushort_t AsH[128 * 64];
    __shared__ __align__(16) ushort_t AsL[128 * 64];
    __shared__ __align__(16) ushort_t BsH[128 * 64];
    __shared__ __align__(16) ushort_t BsL[128 * 64];
    int tid = threadIdx.x;
    int w = tid >> 6, l = tid & 63;
    int m0 = blockIdx.y * 128, n0 = blockIdx.x * 128;
    int wm = (w >> 1) * 64, wn = (w & 1) * 64;

    f32x4 acc[4][4];
#pragma unroll
    for (int i = 0; i < 4; ++i)
#pragma unroll
        for (int j = 0; j < 4; ++j) acc[i][j] = (f32x4)0.f;

    for (int k0 = 0; k0 < K; k0 += 64) {
        int tap = 0, c0 = 0;
        if (PAD) { tap = k0 >> DIN_SHIFT; c0 = k0 & ((1 << DIN_SHIFT) - 1); }
#pragma unroll
        for (int i = 0; i < 4; ++i) {
            int q = i * 256 + tid;            // chunk index 0..1023
            int r = q >> 3;
            int cs = (q & 7) ^ (r & 7);       // swizzled source chunk
            size_t goffA;
            if (PAD) {
                int row = m0 + r;
                int rg = (row >> 9) * LP_ + (row & (L_ - 1)) + tap;
                goffA = ((size_t)rg << DIN_SHIFT) + c0 + cs * 8;
            } else {
                goffA = (size_t)(m0 + r) * K + k0 + cs * 8;
            }
            size_t goffB = (size_t)(n0 + r) * K + k0 + cs * 8;
            size_t lbase = (size_t)(i * 256 + w * 64) * 8;  // wave-uniform
            GLOAD_LDS16(Ahi + goffA, AsH + lbase);
            GLOAD_LDS16(Alo + goffA, AsL + lbase);
            GLOAD_LDS16(Bhi + goffB, BsH + lbase);
            GLOAD_LDS16(Blo + goffB, BsL + lbase);
        }
        __syncthreads();
#pragma unroll
        for (int ks = 0; ks < 2; ++ks) {
            short8 afh[4], afl[4], bfh[4], bfl[4];
#pragma unroll
            for (int t = 0; t < 4; ++t) {
                int rA = wm + t * 16 + (l & 15);
                int cA = (ks * 4 + (l >> 4)) ^ (rA & 7);
                afh[t] = *(const short8*)(AsH + ((size_t)rA * 8 + cA) * 8);
                afl[t] = *(const short8*)(AsL + ((size_t)rA * 8 + cA) * 8);
                int rB = wn + t * 16 + (l & 15);
                int cB = (ks * 4 + (l >> 4)) ^ (rB & 7);
                bfh[t] = *(const short8*)(BsH + ((size_t)rB * 8 + cB) * 8);
                bfl[t] = *(const short8*)(BsL + ((size_t)rB * 8 + cB) * 8);
            }
#pragma unroll
            for (int i = 0; i < 4; ++i)
#pragma unroll
                for (int j = 0; j < 4; ++j) {
                    acc[i][j] = __builtin_amdgcn_mfma_f32_16x16x32_bf16(afh[i], bfh[j], acc[i][j], 0, 0, 0);
                    acc[i][j] = __builtin_amdgcn_mfma_f32_16x16x32_bf16(afl[i], bfh[j], acc[i][j], 0, 0, 0);
                    acc[i][j] = __builtin_amdgcn_mfma_f32_16x16x32_bf16(afh[i], bfl[j], acc[i][j], 0, 0, 0);
                }
        }
        __syncthreads();
    }
    // epilogue.  C/D layout: col = lane&15, row = (lane>>4)*4 + reg
#pragma unroll
    for (int i = 0; i < 4; ++i) {
#pragma unroll
        for (int j = 0; j < 4; ++j) {
#pragma unroll
            for (int r = 0; r < 4; ++r) {
                int row = m0 + wm + i * 16 + (l >> 4) * 4 + r;
                int col = n0 + wn + j * 16 + (l & 15);
                float v = acc[i][j][r];
                if (HAS_BIAS) v += bias[col];
                if (RELU) v = fmaxf(v, 0.f);
                size_t off;
                if (OUT_MODE == 3) off = (size_t)((row >> 9) * LP_ + (row & (L_ - 1)) + 1) * N + col;
                else               off = (size_t)row * N + col;
                if (OUT_MODE == 0) {
                    ((float*)C)[off] = v;
                } else if (OUT_MODE == 1) {
                    float* Cf = (float*)C;
                    Cf[off] += v;
                } else {
                    ushort_t hi = f2bf(v);
                    ((ushort_t*)C)[off] = hi;
                    Clo[off] = f2bf(v - bf2f(hi));
                }
            }
        }
    }
}

// ---------------------------------------------------------------------------
// Attention (fp32): one block per (qi, h, b); q/k/v packed in qkv fp32 buffer
// with row stride 3*D_ (q | k | v).  Output ctx split bf16.
__global__ __launch_bounds__(256) void attn_kernel(const float* __restrict__ qkv,
                                                   ushort_t* __restrict__ ctxh,
                                                   ushort_t* __restrict__ ctxl) {
    int qi = blockIdx.x, h = blockIdx.y, b = blockIdx.z;
    __shared__ float qs[64];
    __shared__ float sc[512];
    __shared__ float red[256];
    __shared__ float part[4][64];
    int tid = threadIdx.x;
    size_t hoff = (size_t)h * DKH_;
    int row = b * L_ + qi;
    size_t qbase = (size_t)row * (3 * D_) + hoff;
    if (tid < 64) qs[tid] = qkv[qbase + tid];
    __syncthreads();
    for (int kk = tid; kk < L_; kk += 256) {
        const float* kr = qkv + (size_t)(b * L_ + kk) * (3 * D_) + D_ + hoff;
        float s = 0.f;
#pragma unroll
        for (int d = 0; d < 64; d += 4) {
            float4 kv = *(const float4*)(kr + d);
            s += qs[d] * kv.x + qs[d + 1] * kv.y + qs[d + 2] * kv.z + qs[d + 3] * kv.w;
        }
        sc[kk] = s;
    }
    __syncthreads();
    float m = fmaxf(sc[tid], sc[tid + 256]);
    red[tid] = m; __syncthreads();
    for (int st = 128; st > 0; st >>= 1) { if (tid < st) red[tid] = fmaxf(red[tid], red[tid + st]); __syncthreads(); }
    float mx = red[0];
    __syncthreads();
    float e0 = expf(sc[tid] - mx), e1 = expf(sc[tid + 256] - mx);
    sc[tid] = e0; sc[tid + 256] = e1;
    red[tid] = e0 + e1; __syncthreads();
    for (int st = 128; st > 0; st >>= 1) { if (tid < st) red[tid] += red[tid + st]; __syncthreads(); }
    float denom = red[0];
    __syncthreads();
    int d = tid & 63, grp = tid >> 6;
    float acc = 0.f;
    for (int kk = grp * 128; kk < grp * 128 + 128; ++kk)
        acc += sc[kk] * qkv[(size_t)(b * L_ + kk) * (3 * D_) + 2 * D_ + hoff + d];
    part[grp][d] = acc;
    __syncthreads();
    if (tid < 64) {
        float r = (part[0][tid] + part[1][tid] + part[2][tid] + part[3][tid]) / denom;
        size_t o = (size_t)row * D_ + hoff + tid;
        ushort_t hi = f2bf(r);
        ctxh[o] = hi;
        ctxl[o] = f2bf(r - bf2f(hi));
    }
}

// ---------------------------------------------------------------------------
__global__ __launch_bounds__(256) void prev_kernel(const float* __restrict__ state,
                                                   float* __restrict__ prev,
                                                   const float* __restrict__ uw) {
    int idx = blockIdx.x * 256 + threadIdx.x;
    int row = idx >> 10;
    float u = uw[row];
    prev[idx] = state[idx] * u + prev[idx] * (1.f - u);
}

// ---------------------------------------------------------------------------
__global__ __launch_bounds__(256) void mean_kernel(const float* __restrict__ prev,
                                                   float* __restrict__ meanbuf) {
    int idx = blockIdx.x * 256 + threadIdx.x;  // 8192
    int b = idx >> 10, d = idx & (D_ - 1);
    float s = 0.f;
    for (int l = 0; l < L_; ++l) s += prev[((size_t)(b * L_ + l) << 10) + d];
    meanbuf[idx] = s * (1.f / L_);
}

// ---------------------------------------------------------------------------
__global__ __launch_bounds__(256) void final_kernel(const float* __restrict__ meanbuf,
                                                    const float* __restrict__ W_out,
                                                    const float* __restrict__ b_out,
                                                    const float* __restrict__ rem,
                                                    const float* __restrict__ nup,
                                                    float* __restrict__ out) {
    int tid = threadIdx.x;
    int grp = tid >> 3;
    int lane = tid & 7;
    int b = grp >> 2, j = grp & 3;
    float s = 0.f;
    for (int d2 = lane; d2 < D_; d2 += 8) s += meanbuf[b * D_ + d2] * W_out[d2 * 4 + j];
    for (int st = 4; st >= 1; st >>= 1) s += __shfl_down(s, st, 8);
    __shared__ float ah[32];
    if (lane == 0) ah[grp] = s + b_out[j];
    __syncthreads();
    if (tid < 8) {
        float a0 = ah[tid * 4 + 0], a1 = ah[tid * 4 + 1], a2 = ah[tid * 4 + 2], a3 = ah[tid * 4 + 3];
        out[tid * 4 + 0] = a0; out[tid * 4 + 1] = a1; out[tid * 4 + 2] = a2; out[tid * 4 + 3] = a3;
        float mx = fmaxf(fmaxf(a0, a1), fmaxf(a2, a3));
        float e0 = expf(a0 - mx), e1 = expf(a1 - mx), e2 = expf(a2 - mx), e3 = expf(a3 - mx);
        float sm = e0 + e1 + e2 + e3;
        out[32 + tid * 4 + 0] = e0 / sm; out[32 + tid * 4 + 1] = e1 / sm;
        out[32 + tid * 4 + 2] = e2 / sm; out[32 + tid * 4 + 3] = e3 / sm;
    }
    for (int i = tid; i < ROWS_; i += 256) {
        out[64 + i] = rem[i];
        out[64 + ROWS_ + i] = nup[i];
    }
}

// ---------------------------------------------------------------------------
extern "C" void kernel_launch(void* const* d_in, const int* in_sizes, int n_in,
                              void* d_out, int out_size, void* d_ws, size_t ws_size,
                              hipStream_t stream) {
    const int*   X     = (const int*)  d_in[0];
    const float* emb   = (const float*)d_in[1];
    const float* p_w   = (const float*)d_in[2];
    const float* p_b   = (const float*)d_in[3];
    const float* Wq    = (const float*)d_in[4];
    const float* Wk    = (const float*)d_in[5];
    const float* Wv    = (const float*)d_in[6];
    const float* Wo    = (const float*)d_in[7];
    const float* ln1_g = (const float*)d_in[8];
    const float* ln1_b = (const float*)d_in[9];
    const float* ln2_g = (const float*)d_in[10];
    const float* ln2_b = (const float*)d_in[11];
    const float* K1    = (const float*)d_in[12];
    const float* c1_b  = (const float*)d_in[13];
    const float* K2    = (const float*)d_in[14];
    const float* c2_b  = (const float*)d_in[15];
    const float* W_out = (const float*)d_in[16];
    const float* b_out = (const float*)d_in[17];

    char* ws = (char*)d_ws;
    size_t off = 0;
    auto alloc = [&](size_t bytes) { char* p = ws + off; off += (bytes + 255) & ~(size_t)255; return p; };

    float*    state  = (float*)alloc(NE_ * 4);
    float*    prev   = (float*)alloc(NE_ * 4);
    ushort_t* xn1h   = (ushort_t*)alloc(NE_ * 2);
    ushort_t* xn1l   = (ushort_t*)alloc(NE_ * 2);
    ushort_t* ctxh   = (ushort_t*)alloc(NE_ * 2);
    ushort_t* ctxl   = (ushort_t*)alloc(NE_ * 2);
    ushort_t* xn2ph  = (ushort_t*)alloc((size_t)B_ * LP_ * D_ * 2);
    ushort_t* xn2pl  = (ushort_t*)alloc((size_t)B_ * LP_ * D_ * 2);
    // union region: qkv fp32 (50.3 MB) aliases h_hi|h_lo (67.4 MB)
    char*     uni    = alloc((size_t)B_ * LP_ * FILT_ * 2 * 2);
    float*    qkv    = (float*)uni;
    ushort_t* hbh    = (ushort_t*)uni;
    ushort_t* hbl    = (ushort_t*)(uni + (size_t)B_ * LP_ * FILT_ * 2);
    ushort_t* WqkvTh = (ushort_t*)alloc((size_t)(3 * D_) * D_ * 2);
    ushort_t* WqkvTl = (ushort_t*)alloc((size_t)(3 * D_) * D_ * 2);
    ushort_t* WoTh   = (ushort_t*)alloc((size_t)D_ * D_ * 2);
    ushort_t* WoTl   = (ushort_t*)alloc((size_t)D_ * D_ * 2);
    ushort_t* K1Th   = (ushort_t*)alloc((size_t)FILT_ * (3 * D_) * 2);
    ushort_t* K1Tl   = (ushort_t*)alloc((size_t)FILT_ * (3 * D_) * 2);
    ushort_t* K2Th   = (ushort_t*)alloc((size_t)D_ * (3 * FILT_) * 2);
    ushort_t* K2Tl   = (ushort_t*)alloc((size_t)D_ * (3 * FILT_) * 2);
    float* hp      = (float*)alloc(ROWS_ * 4);
    float* rem     = (float*)alloc(ROWS_ * 4);
    float* nup     = (float*)alloc(ROWS_ * 4);
    float* uw      = (float*)alloc(ROWS_ * 4);
    float* meanbuf = (float*)alloc(B_ * D_ * 4);

    hipMemsetAsync(prev, 0, NE_ * 4, stream);
    hipMemsetAsync(hp, 0, ROWS_ * 4, stream);
    hipMemsetAsync(rem, 0, ROWS_ * 4, stream);
    hipMemsetAsync(nup, 0, ROWS_ * 4, stream);

    // weight prep: transpose + split; fold q-scale 0.125 (exact pow2) into Wq
    transpose_split_kernel<<<dim3(32, 32), 256, 0, stream>>>(Wq, WqkvTh, WqkvTl, D_, D_, D_, 0, 0,       0.125f);
    transpose_split_kernel<<<dim3(32, 32), 256, 0, stream>>>(Wk, WqkvTh, WqkvTl, D_, D_, D_, 0, D_,      1.f);
    transpose_split_kernel<<<dim3(32, 32), 256, 0, stream>>>(Wv, WqkvTh, WqkvTl, D_, D_, D_, 0, 2 * D_,  1.f);
    transpose_split_kernel<<<dim3(32, 32), 256, 0, stream>>>(Wo, WoTh, WoTl, D_, D_, D_, 0, 0, 1.f);
    for (int t = 0; t < 3; ++t) {
        transpose_split_kernel<<<dim3(128, 32), 256, 0, stream>>>(
            K1 + (size_t)t * D_ * FILT_, K1Th, K1Tl, D_, FILT_, 3 * D_, t * D_, 0, 1.f);
        transpose_split_kernel<<<dim3(32, 128), 256, 0, stream>>>(
            K2 + (size_t)t * FILT_ * D_, K2Th, K2Tl, FILT_, D_, 3 * FILT_, t * FILT_, 0, 1.f);
    }

    embed_kernel<<<ROWS_, 256, 0, stream>>>(X, emb, state);

    dim3 gQKV(3 * D_ / 128, ROWS_ / 128);  // (24, 32)
    dim3 gWo(D_ / 128, ROWS_ / 128);       // (8, 32)
    dim3 gC1(FILT_ / 128, ROWS_ / 128);    // (32, 32)

    for (int t = 0; t < NLAYERS_; ++t) {
        add_sig_kernel<<<NE_ / 256, 256, 0, stream>>>(state, t);
        act_kernel<<<ROWS_, 256, 0, stream>>>(state, p_w, p_b, hp, rem, nup, uw);
        ln_kernel<0><<<ROWS_, 256, 0, stream>>>(state, ln1_g, ln1_b, xn1h, xn1l);

        // qkv = xn @ [0.125*Wq | Wk | Wv]  (fp32 out)
        mfma_gemm<0,0,0,0,0><<<gQKV, 256, 0, stream>>>(xn1h, xn1l, WqkvTh, WqkvTl,
                                                       qkv, nullptr, nullptr, ROWS_, 3 * D_, D_);
        attn_kernel<<<dim3(L_, H_, B_), 256, 0, stream>>>(qkv, ctxh, ctxl);

        // state += ctx @ Wo
        mfma_gemm<0,0,1,0,0><<<gWo, 256, 0, stream>>>(ctxh, ctxl, WoTh, WoTl,
                                                      state, nullptr, nullptr, ROWS_, D_, D_);

        // re-zero conv halos (h region was clobbered by qkv) — qkv now dead
        zero_halo_kernel<<<81920 / 256, 256, 0, stream>>>(xn2ph, xn2pl, hbh, hbl);

        ln_kernel<1><<<ROWS_, 256, 0, stream>>>(state, ln2_g, ln2_b, xn2ph, xn2pl);

        // h = relu(conv1(xn2) + c1_b)  -> padded split bf16
        mfma_gemm<1,10,3,1,1><<<gC1, 256, 0, stream>>>(xn2ph, xn2pl, K1Th, K1Tl,
                                                       hbh, hbl, c1_b, ROWS_, FILT_, 3 * D_);
        // state += conv2(h) + c2_b
        mfma_gemm<1,12,1,0,1><<<gWo, 256, 0, stream>>>(hbh, hbl, K2Th, K2Tl,
                                                       state, nullptr, c2_b, ROWS_, D_, 3 * FILT_);

        prev_kernel<<<NE_ / 256, 256, 0, stream>>>(state, prev, uw);
    }

    mean_kernel<<<(B_ * D_) / 256, 256, 0, stream>>>(prev, meanbuf);
    final_kernel<<<1, 256, 0, stream>>>(meanbuf, W_out, b_out, rem, nup, (float*)d_out);
}

// Round 4
// 6322.016 us; speedup vs baseline: 5.0874x; 2.2261x over previous
//
#include <hip/hip_runtime.h>
#include <math.h>

// Problem constants
#define B_   8
#define L_   512
#define LP_  514                 // padded rows per batch (halo row each side)
#define D_   1024
#define H_   16
#define DKH_ 64
#define FILT_ 4096
#define NLAYERS_ 6
#define ROWS_ (B_*L_)            // 4096
#define NE_   ((size_t)ROWS_*D_) // 4194304 elems per (B,L,D) tensor

typedef unsigned short ushort_t;
typedef unsigned int uint_t;
using short8 = __attribute__((ext_vector_type(8))) short;
using f32x4  = __attribute__((ext_vector_type(4))) float;

typedef const __attribute__((address_space(1))) void* gas_ptr;
typedef __attribute__((address_space(3))) void* las_ptr;
#define GLOAD_LDS16(g, s) __builtin_amdgcn_global_load_lds((gas_ptr)(g), (las_ptr)(s), 16, 0, 0)

__device__ __forceinline__ float bf2f(ushort_t h) { return __uint_as_float((uint_t)h << 16); }
__device__ __forceinline__ ushort_t f2bf(float f) {
    uint_t u = __float_as_uint(f);
    u = (u + 0x7FFFu + ((u >> 16) & 1u)) >> 16;   // RNE
    return (ushort_t)u;
}

// ---------------------------------------------------------------------------
__global__ __launch_bounds__(256) void embed_kernel(const int* __restrict__ X,
                                                    const float* __restrict__ emb,
                                                    float* __restrict__ state) {
    int row = blockIdx.x;
    int tok = X[row];
    const float4* src = (const float4*)(emb + (size_t)tok * D_);
    float4* dst = (float4*)(state + (size_t)row * D_);
    dst[threadIdx.x] = src[threadIdx.x];
}

// ---------------------------------------------------------------------------
// Precompute TIME_SIG (L x D) and POS_SIG (NLAYERS x D) once per launch.
__global__ __launch_bounds__(256) void sig_kernel(float* __restrict__ timesig,
                                                  float* __restrict__ possig) {
    int idx = blockIdx.x * 256 + threadIdx.x;      // L_*D_ = 524288
    int c = idx & (D_ - 1);
    int l = idx >> 10;
    const float log_inc = 0.0180241494559220821f;  // log(10000)/511
    int j = c & 511;
    float inv = expf(-log_inc * (float)j);
    timesig[idx] = (c < 512) ? sinf((float)l * inv) : cosf((float)l * inv);
    if (l < NLAYERS_)
        possig[idx] = (c < 512) ? sinf((float)l * inv) : cosf((float)l * inv);
}

// state += TIME_SIG[l,c] + POS_SIG[t,c]   (memory-bound now)
__global__ __launch_bounds__(256) void add_sig_kernel(float* __restrict__ state,
                                                      const float* __restrict__ timesig,
                                                      const float* __restrict__ possig,
                                                      int layer_t) {
    int idx = blockIdx.x * 256 + threadIdx.x;
    int c = idx & (D_ - 1);
    int tl = idx & (L_ * D_ - 1);
    state[idx] += timesig[tl] + possig[layer_t * D_ + c];
}

// ---------------------------------------------------------------------------
__global__ __launch_bounds__(256) void act_kernel(const float* __restrict__ state,
                                                  const float* __restrict__ p_w,
                                                  const float* __restrict__ p_b,
                                                  float* __restrict__ hp, float* __restrict__ rem,
                                                  float* __restrict__ nup, float* __restrict__ uw) {
    int row = blockIdx.x;
    const float* x = state + (size_t)row * D_;
    float s = 0.f;
    for (int i = threadIdx.x; i < D_; i += 256) s += x[i] * p_w[i];
    __shared__ float red[256];
    red[threadIdx.x] = s; __syncthreads();
    for (int st = 128; st > 0; st >>= 1) {
        if (threadIdx.x < st) red[threadIdx.x] += red[threadIdx.x + st];
        __syncthreads();
    }
    if (threadIdx.x == 0) {
        float p = 1.f / (1.f + expf(-(red[0] + p_b[0])));
        float h = hp[row], r = rem[row], n = nup[row];
        float still = (h < 1.0f) ? 1.f : 0.f;
        float add = h + p * still;
        float nh     = (add > 0.9f) ? still : 0.f;
        float still2 = (add <= 0.9f) ? still : 0.f;
        h += p * still2;
        r += nh * (1.f - h);
        h += nh * r;
        n += still2 + nh;
        hp[row] = h; rem[row] = r; nup[row] = n;
        uw[row] = p * still2 + nh * r;
    }
}

// ---------------------------------------------------------------------------
// LayerNorm (ddof=1), fp32 in, split bf16 hi/lo out.  OUT_PAD: padded layout.
template<int OUT_PAD>
__global__ __launch_bounds__(256) void ln_kernel(const float* __restrict__ x,
                                                 const float* __restrict__ g,
                                                 const float* __restrict__ b,
                                                 ushort_t* __restrict__ yh,
                                                 ushort_t* __restrict__ yl) {
    int row = blockIdx.x;
    const float4* xr = (const float4*)(x + (size_t)row * D_);
    float4 v = xr[threadIdx.x];
    __shared__ float red[256];
    float s = v.x + v.y + v.z + v.w;
    red[threadIdx.x] = s; __syncthreads();
    for (int st = 128; st > 0; st >>= 1) { if (threadIdx.x < st) red[threadIdx.x] += red[threadIdx.x + st]; __syncthreads(); }
    float mu = red[0] * (1.f / D_);
    __syncthreads();
    float dx0 = v.x - mu, dx1 = v.y - mu, dx2 = v.z - mu, dx3 = v.w - mu;
    red[threadIdx.x] = dx0*dx0 + dx1*dx1 + dx2*dx2 + dx3*dx3; __syncthreads();
    for (int st = 128; st > 0; st >>= 1) { if (threadIdx.x < st) red[threadIdx.x] += red[threadIdx.x + st]; __syncthreads(); }
    float sd = sqrtf(red[0] * (1.f / (D_ - 1)));
    float inv = 1.f / (sd + 1e-6f);
    const float4* g4 = (const float4*)g;
    const float4* b4 = (const float4*)b;
    float4 gv = g4[threadIdx.x], bv = b4[threadIdx.x];
    float o0 = gv.x * dx0 * inv + bv.x;
    float o1 = gv.y * dx1 * inv + bv.y;
    float o2 = gv.z * dx2 * inv + bv.z;
    float o3 = gv.w * dx3 * inv + bv.w;
    int orow = OUT_PAD ? ((row >> 9) * LP_ + (row & (L_ - 1)) + 1) : row;
    ushort4 oh, ol;
    oh.x = f2bf(o0); ol.x = f2bf(o0 - bf2f(oh.x));
    oh.y = f2bf(o1); ol.y = f2bf(o1 - bf2f(oh.y));
    oh.z = f2bf(o2); ol.z = f2bf(o2 - bf2f(oh.z));
    oh.w = f2bf(o3); ol.w = f2bf(o3 - bf2f(oh.w));
    ((ushort4*)(yh + (size_t)orow * D_))[threadIdx.x] = oh;
    ((ushort4*)(yl + (size_t)orow * D_))[threadIdx.x] = ol;
}

// ---------------------------------------------------------------------------
// Transpose + split: dst[nbase+c][kbase+r] = split(scale * src[r][c])
__global__ __launch_bounds__(256) void transpose_split_kernel(const float* __restrict__ src,
                                                              ushort_t* __restrict__ dhi,
                                                              ushort_t* __restrict__ dlo,
                                                              int R, int C, int dstride,
                                                              int kbase, int nbase, float scale) {
    __shared__ float tile[32][33];
    int tx = threadIdx.x & 31, ty = threadIdx.x >> 5;   // 32 x 8
    int r0 = blockIdx.y * 32, c0 = blockIdx.x * 32;
#pragma unroll
    for (int i = 0; i < 4; ++i)
        tile[ty + i * 8][tx] = src[(size_t)(r0 + ty + i * 8) * C + c0 + tx] * scale;
    __syncthreads();
#pragma unroll
    for (int i = 0; i < 4; ++i) {
        int c = c0 + ty + i * 8;
        float val = tile[tx][ty + i * 8];
        ushort_t hi = f2bf(val);
        ushort_t lo = f2bf(val - bf2f(hi));
        size_t idx = (size_t)(nbase + c) * dstride + kbase + r0 + tx;
        dhi[idx] = hi; dlo[idx] = lo;
    }
}

// ---------------------------------------------------------------------------
// Zero halo rows of all four padded activation buffers
__global__ __launch_bounds__(256) void zero_halo_kernel(ushort_t* __restrict__ xh,
                                                        ushort_t* __restrict__ xl,
                                                        ushort_t* __restrict__ hh,
                                                        ushort_t* __restrict__ hl) {
    int idx = blockIdx.x * 256 + threadIdx.x;          // 81920 total
    if (idx < 16384) {
        int b = idx >> 11, r = (idx >> 10) & 1, c = idx & 1023;
        size_t o = ((size_t)b * LP_ + r * (LP_ - 1)) * D_ + c;
        xh[o] = 0; xl[o] = 0;
    } else {
        int j = idx - 16384;
        int b = j >> 13, r = (j >> 12) & 1, c = j & 4095;
        size_t o = ((size_t)b * LP_ + r * (LP_ - 1)) * FILT_ + c;
        hh[o] = 0; hl[o] = 0;
    }
}

// ---------------------------------------------------------------------------
// bf16x3 MFMA GEMM (unchanged from round 3)
template<int PAD, int DIN_SHIFT, int OUT_MODE, int RELU, int HAS_BIAS>
__global__ __launch_bounds__(256) void mfma_gemm(const ushort_t* __restrict__ Ahi,
                                                 const ushort_t* __restrict__ Alo,
                                                 const ushort_t* __restrict__ Bhi,
                                                 const ushort_t* __restrict__ Blo,
                                                 void* __restrict__ C,
                                                 ushort_t* __restrict__ Clo,
                                                 const float* __restrict__ bias,
                                                 int M, int N, int K) {
    __shared__ __align__(16) ushort_t AsH[128 * 64];
    __shared__ __align__(16) ushort_t AsL[128 * 64];
    __shared__ __align__(16) ushort_t BsH[128 * 64];
    __shared__ __align__(16) ushort_t BsL[128 * 64];
    int tid = threadIdx.x;
    int w = tid >> 6, l = tid & 63;
    int m0 = blockIdx.y * 128, n0 = blockIdx.x * 128;
    int wm = (w >> 1) * 64, wn = (w & 1) * 64;

    f32x4 acc[4][4];
#pragma unroll
    for (int i = 0; i < 4; ++i)
#pragma unroll
        for (int j = 0; j < 4; ++j) acc[i][j] = (f32x4)0.f;

    for (int k0 = 0; k0 < K; k0 += 64) {
        int tap = 0, c0 = 0;
        if (PAD) { tap = k0 >> DIN_SHIFT; c0 = k0 & ((1 << DIN_SHIFT) - 1); }
#pragma unroll
        for (int i = 0; i < 4; ++i) {
            int q = i * 256 + tid;
            int r = q >> 3;
            int cs = (q & 7) ^ (r & 7);
            size_t goffA;
            if (PAD) {
                int row = m0 + r;
                int rg = (row >> 9) * LP_ + (row & (L_ - 1)) + tap;
                goffA = ((size_t)rg << DIN_SHIFT) + c0 + cs * 8;
            } else {
                goffA = (size_t)(m0 + r) * K + k0 + cs * 8;
            }
            size_t goffB = (size_t)(n0 + r) * K + k0 + cs * 8;
            size_t lbase = (size_t)(i * 256 + w * 64) * 8;
            GLOAD_LDS16(Ahi + goffA, AsH + lbase);
            GLOAD_LDS16(Alo + goffA, AsL + lbase);
            GLOAD_LDS16(Bhi + goffB, BsH + lbase);
            GLOAD_LDS16(Blo + goffB, BsL + lbase);
        }
        __syncthreads();
#pragma unroll
        for (int ks = 0; ks < 2; ++ks) {
            short8 afh[4], afl[4], bfh[4], bfl[4];
#pragma unroll
            for (int t = 0; t < 4; ++t) {
                int rA = wm + t * 16 + (l & 15);
                int cA = (ks * 4 + (l >> 4)) ^ (rA & 7);
                afh[t] = *(const short8*)(AsH + ((size_t)rA * 8 + cA) * 8);
                afl[t] = *(const short8*)(AsL + ((size_t)rA * 8 + cA) * 8);
                int rB = wn + t * 16 + (l & 15);
                int cB = (ks * 4 + (l >> 4)) ^ (rB & 7);
                bfh[t] = *(const short8*)(BsH + ((size_t)rB * 8 + cB) * 8);
                bfl[t] = *(const short8*)(BsL + ((size_t)rB * 8 + cB) * 8);
            }
#pragma unroll
            for (int i = 0; i < 4; ++i)
#pragma unroll
                for (int j = 0; j < 4; ++j) {
                    acc[i][j] = __builtin_amdgcn_mfma_f32_16x16x32_bf16(afh[i], bfh[j], acc[i][j], 0, 0, 0);
                    acc[i][j] = __builtin_amdgcn_mfma_f32_16x16x32_bf16(afl[i], bfh[j], acc[i][j], 0, 0, 0);
                    acc[i][j] = __builtin_amdgcn_mfma_f32_16x16x32_bf16(afh[i], bfl[j], acc[i][j], 0, 0, 0);
                }
        }
        __syncthreads();
    }
#pragma unroll
    for (int i = 0; i < 4; ++i) {
#pragma unroll
        for (int j = 0; j < 4; ++j) {
#pragma unroll
            for (int r = 0; r < 4; ++r) {
                int row = m0 + wm + i * 16 + (l >> 4) * 4 + r;
                int col = n0 + wn + j * 16 + (l & 15);
                float v = acc[i][j][r];
                if (HAS_BIAS) v += bias[col];
                if (RELU) v = fmaxf(v, 0.f);
                size_t off;
                if (OUT_MODE == 3) off = (size_t)((row >> 9) * LP_ + (row & (L_ - 1)) + 1) * N + col;
                else               off = (size_t)row * N + col;
                if (OUT_MODE == 0) {
                    ((float*)C)[off] = v;
                } else if (OUT_MODE == 1) {
                    float* Cf = (float*)C;
                    Cf[off] += v;
                } else {
                    ushort_t hi = f2bf(v);
                    ((ushort_t*)C)[off] = hi;
                    Clo[off] = f2bf(v - bf2f(hi));
                }
            }
        }
    }
}

// ---------------------------------------------------------------------------
// V transpose+split: Vt[b,h,d,key] (hi/lo bf16) from qkv fp32 V-section.
__global__ __launch_bounds__(256) void vt_kernel(const float* __restrict__ qkv,
                                                 ushort_t* __restrict__ Vth,
                                                 ushort_t* __restrict__ Vtl) {
    __shared__ float t[64][65];
    int kt = blockIdx.x, h = blockIdx.y, b = blockIdx.z;
    int tx = threadIdx.x & 63, ty = threadIdx.x >> 6;  // 64 x 4
#pragma unroll
    for (int i = 0; i < 16; ++i) {
        int r = ty + i * 4;            // key within tile
        t[r][tx] = qkv[(size_t)(b * L_ + kt * 64 + r) * (3 * D_) + 2 * D_ + h * DKH_ + tx];
    }
    __syncthreads();
#pragma unroll
    for (int i = 0; i < 16; ++i) {
        int d = ty + i * 4;
        float v = t[tx][d];            // key=tx, dim=d
        size_t o = ((size_t)((b * H_ + h) * DKH_ + d)) * L_ + kt * 64 + tx;
        ushort_t hj = f2bf(v);
        Vth[o] = hj; Vtl[o] = f2bf(v - bf2f(hj));
    }
}

// ---------------------------------------------------------------------------
// Flash MFMA attention, bf16x3 split precision (~fp32), online softmax.
// Block = (qtile of 128, h, b); 4 waves, each owns 32 q rows.
// Q,K read from fp32 qkv (split in-register); V from pre-transposed Vt.
// P round-trips per-wave LDS (row stride 136 elems = 17 16B-chunks, odd).
__global__ __launch_bounds__(256, 2) void fattn_kernel(const float* __restrict__ qkv,
                                                       const ushort_t* __restrict__ Vth,
                                                       const ushort_t* __restrict__ Vtl,
                                                       ushort_t* __restrict__ ctxh,
                                                       ushort_t* __restrict__ ctxl) {
    __shared__ __align__(16) ushort_t Ph[4][32 * 136];
    __shared__ __align__(16) ushort_t Pl[4][32 * 136];
    int qt = blockIdx.x, h = blockIdx.y, b = blockIdx.z;
    int w = threadIdx.x >> 6, l = threadIdx.x & 63;
    int lm = l & 15, lq = l >> 4;
    int q0 = qt * 128 + w * 32;

    // Q fragments (constant across chunks): A[m=lm][k=lq*8+j]
    short8 qfh[2][2], qfl[2][2];
#pragma unroll
    for (int mt = 0; mt < 2; ++mt)
#pragma unroll
        for (int ks = 0; ks < 2; ++ks) {
            const float* qp = qkv + (size_t)(b * L_ + q0 + mt * 16 + lm) * (3 * D_)
                              + h * DKH_ + ks * 32 + lq * 8;
            short8 hi, lo;
#pragma unroll
            for (int j = 0; j < 8; ++j) {
                float x = qp[j];
                ushort_t hj = f2bf(x);
                hi[j] = (short)hj;
                lo[j] = (short)f2bf(x - bf2f(hj));
            }
            qfh[mt][ks] = hi; qfl[mt][ks] = lo;
        }

    float mrow[2][4], lrow[2][4];
    f32x4 oacc[2][4];
#pragma unroll
    for (int mt = 0; mt < 2; ++mt)
#pragma unroll
        for (int r = 0; r < 4; ++r) { mrow[mt][r] = -3.0e38f; lrow[mt][r] = 0.f; }
#pragma unroll
    for (int mt = 0; mt < 2; ++mt)
#pragma unroll
        for (int nt = 0; nt < 4; ++nt) oacc[mt][nt] = (f32x4)0.f;

    for (int c = 0; c < 4; ++c) {           // key chunks of 128
        f32x4 s[2][8];
#pragma unroll
        for (int mt = 0; mt < 2; ++mt)
#pragma unroll
            for (int nt = 0; nt < 8; ++nt) s[mt][nt] = (f32x4)0.f;

        // S = Q K^T  (bf16x3)
#pragma unroll
        for (int nt = 0; nt < 8; ++nt) {
#pragma unroll
            for (int ks = 0; ks < 2; ++ks) {
                const float* kp = qkv + (size_t)(b * L_ + c * 128 + nt * 16 + lm) * (3 * D_)
                                  + D_ + h * DKH_ + ks * 32 + lq * 8;
                short8 kh, kl;
#pragma unroll
                for (int j = 0; j < 8; ++j) {
                    float x = kp[j];
                    ushort_t hj = f2bf(x);
                    kh[j] = (short)hj;
                    kl[j] = (short)f2bf(x - bf2f(hj));
                }
#pragma unroll
                for (int mt = 0; mt < 2; ++mt) {
                    s[mt][nt] = __builtin_amdgcn_mfma_f32_16x16x32_bf16(qfh[mt][ks], kh, s[mt][nt], 0, 0, 0);
                    s[mt][nt] = __builtin_amdgcn_mfma_f32_16x16x32_bf16(qfl[mt][ks], kh, s[mt][nt], 0, 0, 0);
                    s[mt][nt] = __builtin_amdgcn_mfma_f32_16x16x32_bf16(qfh[mt][ks], kl, s[mt][nt], 0, 0, 0);
                }
            }
        }

        // online softmax: C-layout row=(lq*4+r), col=lm per 16x16 tile
#pragma unroll
        for (int mt = 0; mt < 2; ++mt) {
#pragma unroll
            for (int r = 0; r < 4; ++r) {
                float cm = s[mt][0][r];
#pragma unroll
                for (int nt = 1; nt < 8; ++nt) cm = fmaxf(cm, s[mt][nt][r]);
                cm = fmaxf(cm, __shfl_xor(cm, 1));
                cm = fmaxf(cm, __shfl_xor(cm, 2));
                cm = fmaxf(cm, __shfl_xor(cm, 4));
                cm = fmaxf(cm, __shfl_xor(cm, 8));
                float mnew = fmaxf(mrow[mt][r], cm);
                float alpha = expf(mrow[mt][r] - mnew);
                mrow[mt][r] = mnew;
                float ps = 0.f;
                int rw = mt * 16 + lq * 4 + r;
#pragma unroll
                for (int nt = 0; nt < 8; ++nt) {
                    float p = expf(s[mt][nt][r] - mnew);
                    ps += p;
                    ushort_t hj = f2bf(p);
                    int cl = nt * 16 + lm;
                    Ph[w][rw * 136 + cl] = hj;
                    Pl[w][rw * 136 + cl] = f2bf(p - bf2f(hj));
                }
                ps += __shfl_xor(ps, 1);
                ps += __shfl_xor(ps, 2);
                ps += __shfl_xor(ps, 4);
                ps += __shfl_xor(ps, 8);
                lrow[mt][r] = lrow[mt][r] * alpha + ps;
#pragma unroll
                for (int nt = 0; nt < 4; ++nt) oacc[mt][nt][r] *= alpha;
            }
        }
        asm volatile("s_waitcnt lgkmcnt(0)" ::: "memory");   // P writes visible to own wave

        // O += P V  (bf16x3).  A[m=lm][k], B[k][n=lm(d)]
#pragma unroll
        for (int ks = 0; ks < 4; ++ks) {
            short8 pah[2], pal[2];
#pragma unroll
            for (int mt = 0; mt < 2; ++mt) {
                pah[mt] = *(const short8*)&Ph[w][(mt * 16 + lm) * 136 + ks * 32 + lq * 8];
                pal[mt] = *(const short8*)&Pl[w][(mt * 16 + lm) * 136 + ks * 32 + lq * 8];
            }
#pragma unroll
            for (int nt = 0; nt < 4; ++nt) {
                size_t vo = ((size_t)((b * H_ + h) * DKH_ + nt * 16 + lm)) * L_ + c * 128 + ks * 32 + lq * 8;
                short8 vh = *(const short8*)(Vth + vo);
                short8 vl = *(const short8*)(Vtl + vo);
#pragma unroll
                for (int mt = 0; mt < 2; ++mt) {
                    oacc[mt][nt] = __builtin_amdgcn_mfma_f32_16x16x32_bf16(pah[mt], vh, oacc[mt][nt], 0, 0, 0);
                    oacc[mt][nt] = __builtin_amdgcn_mfma_f32_16x16x32_bf16(pal[mt], vh, oacc[mt][nt], 0, 0, 0);
                    oacc[mt][nt] = __builtin_amdgcn_mfma_f32_16x16x32_bf16(pah[mt], vl, oacc[mt][nt], 0, 0, 0);
                }
            }
        }
        asm volatile("s_waitcnt lgkmcnt(0)" ::: "memory");   // P reads done before next overwrite
    }

    // epilogue: ctx = O / l, split bf16
#pragma unroll
    for (int mt = 0; mt < 2; ++mt) {
#pragma unroll
        for (int nt = 0; nt < 4; ++nt) {
#pragma unroll
            for (int r = 0; r < 4; ++r) {
                float v = oacc[mt][nt][r] / lrow[mt][r];
                int rowg = b * L_ + qt * 128 + w * 32 + mt * 16 + lq * 4 + r;
                int colg = h * DKH_ + nt * 16 + lm;
                size_t o = (size_t)rowg * D_ + colg;
                ushort_t hj = f2bf(v);
                ctxh[o] = hj;
                ctxl[o] = f2bf(v - bf2f(hj));
            }
        }
    }
}

// ---------------------------------------------------------------------------
__global__ __launch_bounds__(256) void prev_kernel(const float* __restrict__ state,
                                                   float* __restrict__ prev,
                                                   const float* __restrict__ uw) {
    int idx = blockIdx.x * 256 + threadIdx.x;
    int row = idx >> 10;
    float u = uw[row];
    prev[idx] = state[idx] * u + prev[idx] * (1.f - u);
}

// ---------------------------------------------------------------------------
__global__ __launch_bounds__(256) void mean_kernel(const float* __restrict__ prev,
                                                   float* __restrict__ meanbuf) {
    int idx = blockIdx.x * 256 + threadIdx.x;  // 8192
    int b = idx >> 10, d = idx & (D_ - 1);
    float s = 0.f;
    for (int l = 0; l < L_; ++l) s += prev[((size_t)(b * L_ + l) << 10) + d];
    meanbuf[idx] = s * (1.f / L_);
}

// ---------------------------------------------------------------------------
__global__ __launch_bounds__(256) void final_kernel(const float* __restrict__ meanbuf,
                                                    const float* __restrict__ W_out,
                                                    const float* __restrict__ b_out,
                                                    const float* __restrict__ rem,
                                                    const float* __restrict__ nup,
                                                    float* __restrict__ out) {
    int tid = threadIdx.x;
    int grp = tid >> 3;
    int lane = tid & 7;
    int b = grp >> 2, j = grp & 3;
    float s = 0.f;
    for (int d2 = lane; d2 < D_; d2 += 8) s += meanbuf[b * D_ + d2] * W_out[d2 * 4 + j];
    for (int st = 4; st >= 1; st >>= 1) s += __shfl_down(s, st, 8);
    __shared__ float ah[32];
    if (lane == 0) ah[grp] = s + b_out[j];
    __syncthreads();
    if (tid < 8) {
        float a0 = ah[tid * 4 + 0], a1 = ah[tid * 4 + 1], a2 = ah[tid * 4 + 2], a3 = ah[tid * 4 + 3];
        out[tid * 4 + 0] = a0; out[tid * 4 + 1] = a1; out[tid * 4 + 2] = a2; out[tid * 4 + 3] = a3;
        float mx = fmaxf(fmaxf(a0, a1), fmaxf(a2, a3));
        float e0 = expf(a0 - mx), e1 = expf(a1 - mx), e2 = expf(a2 - mx), e3 = expf(a3 - mx);
        float sm = e0 + e1 + e2 + e3;
        out[32 + tid * 4 + 0] = e0 / sm; out[32 + tid * 4 + 1] = e1 / sm;
        out[32 + tid * 4 + 2] = e2 / sm; out[32 + tid * 4 + 3] = e3 / sm;
    }
    for (int i = tid; i < ROWS_; i += 256) {
        out[64 + i] = rem[i];
        out[64 + ROWS_ + i] = nup[i];
    }
}

// ---------------------------------------------------------------------------
extern "C" void kernel_launch(void* const* d_in, const int* in_sizes, int n_in,
                              void* d_out, int out_size, void* d_ws, size_t ws_size,
                              hipStream_t stream) {
    const int*   X     = (const int*)  d_in[0];
    const float* emb   = (const float*)d_in[1];
    const float* p_w   = (const float*)d_in[2];
    const float* p_b   = (const float*)d_in[3];
    const float* Wq    = (const float*)d_in[4];
    const float* Wk    = (const float*)d_in[5];
    const float* Wv    = (const float*)d_in[6];
    const float* Wo    = (const float*)d_in[7];
    const float* ln1_g = (const float*)d_in[8];
    const float* ln1_b = (const float*)d_in[9];
    const float* ln2_g = (const float*)d_in[10];
    const float* ln2_b = (const float*)d_in[11];
    const float* K1    = (const float*)d_in[12];
    const float* c1_b  = (const float*)d_in[13];
    const float* K2    = (const float*)d_in[14];
    const float* c2_b  = (const float*)d_in[15];
    const float* W_out = (const float*)d_in[16];
    const float* b_out = (const float*)d_in[17];

    char* ws = (char*)d_ws;
    size_t off = 0;
    auto alloc = [&](size_t bytes) { char* p = ws + off; off += (bytes + 255) & ~(size_t)255; return p; };

    float*    state  = (float*)alloc(NE_ * 4);
    float*    prev   = (float*)alloc(NE_ * 4);
    ushort_t* xn1h   = (ushort_t*)alloc(NE_ * 2);
    ushort_t* xn1l   = (ushort_t*)alloc(NE_ * 2);
    ushort_t* ctxh   = (ushort_t*)alloc(NE_ * 2);
    ushort_t* ctxl   = (ushort_t*)alloc(NE_ * 2);
    ushort_t* xn2ph  = (ushort_t*)alloc((size_t)B_ * LP_ * D_ * 2);
    ushort_t* xn2pl  = (ushort_t*)alloc((size_t)B_ * LP_ * D_ * 2);
    // union region (67.37 MB): [ qkv fp32 50.33 MB | Vth 8.39 | Vtl 8.39 ]
    // later aliased by h_hi|h_lo padded conv buffers
    char*     uni    = alloc((size_t)B_ * LP_ * FILT_ * 2 * 2);
    float*    qkv    = (float*)uni;
    ushort_t* Vth    = (ushort_t*)(uni + (size_t)ROWS_ * 3 * D_ * 4);
    ushort_t* Vtl    = Vth + (size_t)B_ * H_ * DKH_ * L_;
    ushort_t* hbh    = (ushort_t*)uni;
    ushort_t* hbl    = (ushort_t*)(uni + (size_t)B_ * LP_ * FILT_ * 2);
    ushort_t* WqkvTh = (ushort_t*)alloc((size_t)(3 * D_) * D_ * 2);
    ushort_t* WqkvTl = (ushort_t*)alloc((size_t)(3 * D_) * D_ * 2);
    ushort_t* WoTh   = (ushort_t*)alloc((size_t)D_ * D_ * 2);
    ushort_t* WoTl   = (ushort_t*)alloc((size_t)D_ * D_ * 2);
    ushort_t* K1Th   = (ushort_t*)alloc((size_t)FILT_ * (3 * D_) * 2);
    ushort_t* K1Tl   = (ushort_t*)alloc((size_t)FILT_ * (3 * D_) * 2);
    ushort_t* K2Th   = (ushort_t*)alloc((size_t)D_ * (3 * FILT_) * 2);
    ushort_t* K2Tl   = (ushort_t*)alloc((size_t)D_ * (3 * FILT_) * 2);
    float* timesig = (float*)alloc((size_t)L_ * D_ * 4);
    float* possig  = (float*)alloc((size_t)NLAYERS_ * D_ * 4);
    float* hp      = (float*)alloc(ROWS_ * 4);
    float* rem     = (float*)alloc(ROWS_ * 4);
    float* nup     = (float*)alloc(ROWS_ * 4);
    float* uw      = (float*)alloc(ROWS_ * 4);
    float* meanbuf = (float*)alloc(B_ * D_ * 4);

    hipMemsetAsync(prev, 0, NE_ * 4, stream);
    hipMemsetAsync(hp, 0, ROWS_ * 4, stream);
    hipMemsetAsync(rem, 0, ROWS_ * 4, stream);
    hipMemsetAsync(nup, 0, ROWS_ * 4, stream);

    // weight prep: transpose + split; fold q-scale 0.125 (exact pow2) into Wq
    transpose_split_kernel<<<dim3(32, 32), 256, 0, stream>>>(Wq, WqkvTh, WqkvTl, D_, D_, D_, 0, 0,       0.125f);
    transpose_split_kernel<<<dim3(32, 32), 256, 0, stream>>>(Wk, WqkvTh, WqkvTl, D_, D_, D_, 0, D_,      1.f);
    transpose_split_kernel<<<dim3(32, 32), 256, 0, stream>>>(Wv, WqkvTh, WqkvTl, D_, D_, D_, 0, 2 * D_,  1.f);
    transpose_split_kernel<<<dim3(32, 32), 256, 0, stream>>>(Wo, WoTh, WoTl, D_, D_, D_, 0, 0, 1.f);
    for (int t = 0; t < 3; ++t) {
        transpose_split_kernel<<<dim3(128, 32), 256, 0, stream>>>(
            K1 + (size_t)t * D_ * FILT_, K1Th, K1Tl, D_, FILT_, 3 * D_, t * D_, 0, 1.f);
        transpose_split_kernel<<<dim3(32, 128), 256, 0, stream>>>(
            K2 + (size_t)t * FILT_ * D_, K2Th, K2Tl, FILT_, D_, 3 * FILT_, t * FILT_, 0, 1.f);
    }
    sig_kernel<<<(L_ * D_) / 256, 256, 0, stream>>>(timesig, possig);

    embed_kernel<<<ROWS_, 256, 0, stream>>>(X, emb, state);

    dim3 gQKV(3 * D_ / 128, ROWS_ / 128);  // (24, 32)
    dim3 gWo(D_ / 128, ROWS_ / 128);       // (8, 32)
    dim3 gC1(FILT_ / 128, ROWS_ / 128);    // (32, 32)

    for (int t = 0; t < NLAYERS_; ++t) {
        add_sig_kernel<<<NE_ / 256, 256, 0, stream>>>(state, timesig, possig, t);
        act_kernel<<<ROWS_, 256, 0, stream>>>(state, p_w, p_b, hp, rem, nup, uw);
        ln_kernel<0><<<ROWS_, 256, 0, stream>>>(state, ln1_g, ln1_b, xn1h, xn1l);

        // qkv = xn @ [0.125*Wq | Wk | Wv]  (fp32 out)
        mfma_gemm<0,0,0,0,0><<<gQKV, 256, 0, stream>>>(xn1h, xn1l, WqkvTh, WqkvTl,
                                                       qkv, nullptr, nullptr, ROWS_, 3 * D_, D_);
        vt_kernel<<<dim3(L_ / 64, H_, B_), 256, 0, stream>>>(qkv, Vth, Vtl);
        fattn_kernel<<<dim3(L_ / 128, H_, B_), 256, 0, stream>>>(qkv, Vth, Vtl, ctxh, ctxl);

        // state += ctx @ Wo
        mfma_gemm<0,0,1,0,0><<<gWo, 256, 0, stream>>>(ctxh, ctxl, WoTh, WoTl,
                                                      state, nullptr, nullptr, ROWS_, D_, D_);

        // re-zero conv halos (h region aliases qkv/Vt — now dead)
        zero_halo_kernel<<<81920 / 256, 256, 0, stream>>>(xn2ph, xn2pl, hbh, hbl);

        ln_kernel<1><<<ROWS_, 256, 0, stream>>>(state, ln2_g, ln2_b, xn2ph, xn2pl);

        // h = relu(conv1(xn2) + c1_b)  -> padded split bf16
        mfma_gemm<1,10,3,1,1><<<gC1, 256, 0, stream>>>(xn2ph, xn2pl, K1Th, K1Tl,
                                                       hbh, hbl, c1_b, ROWS_, FILT_, 3 * D_);
        // state += conv2(h) + c2_b
        mfma_gemm<1,12,1,0,1><<<gWo, 256, 0, stream>>>(hbh, hbl, K2Th, K2Tl,
                                                       state, nullptr, c2_b, ROWS_, D_, 3 * FILT_);

        prev_kernel<<<NE_ / 256, 256, 0, stream>>>(state, prev, uw);
    }

    mean_kernel<<<(B_ * D_) / 256, 256, 0, stream>>>(prev, meanbuf);
    final_kernel<<<1, 256, 0, stream>>>(meanbuf, W_out, b_out, rem, nup, (float*)d_out);
}

// Round 5
// 5452.023 us; speedup vs baseline: 5.8992x; 1.1596x over previous
//
#include <hip/hip_runtime.h>
#include <math.h>

// Problem constants
#define B_   8
#define L_   512
#define LP_  514                 // padded rows per batch (halo row each side)
#define D_   1024
#define H_   16
#define DKH_ 64
#define FILT_ 4096
#define NLAYERS_ 6
#define ROWS_ (B_*L_)            // 4096
#define NE_   ((size_t)ROWS_*D_) // 4194304 elems per (B,L,D) tensor

typedef unsigned short ushort_t;
typedef unsigned int uint_t;
using short8 = __attribute__((ext_vector_type(8))) short;
using f32x4  = __attribute__((ext_vector_type(4))) float;

typedef const __attribute__((address_space(1))) void* gas_ptr;
typedef __attribute__((address_space(3))) void* las_ptr;
#define GLOAD_LDS16(g, s) __builtin_amdgcn_global_load_lds((gas_ptr)(g), (las_ptr)(s), 16, 0, 0)

__device__ __forceinline__ float bf2f(ushort_t h) { return __uint_as_float((uint_t)h << 16); }
__device__ __forceinline__ ushort_t f2bf(float f) {
    uint_t u = __float_as_uint(f);
    u = (u + 0x7FFFu + ((u >> 16) & 1u)) >> 16;   // RNE
    return (ushort_t)u;
}

// ---------------------------------------------------------------------------
__global__ __launch_bounds__(256) void embed_kernel(const int* __restrict__ X,
                                                    const float* __restrict__ emb,
                                                    float* __restrict__ state) {
    int row = blockIdx.x;
    int tok = X[row];
    const float4* src = (const float4*)(emb + (size_t)tok * D_);
    float4* dst = (float4*)(state + (size_t)row * D_);
    dst[threadIdx.x] = src[threadIdx.x];
}

// ---------------------------------------------------------------------------
// Precompute TIME_SIG (L x D) and POS_SIG (NLAYERS x D) once per launch.
__global__ __launch_bounds__(256) void sig_kernel(float* __restrict__ timesig,
                                                  float* __restrict__ possig) {
    int idx = blockIdx.x * 256 + threadIdx.x;      // L_*D_ = 524288
    int c = idx & (D_ - 1);
    int l = idx >> 10;
    const float log_inc = 0.0180241494559220821f;  // log(10000)/511
    int j = c & 511;
    float inv = expf(-log_inc * (float)j);
    timesig[idx] = (c < 512) ? sinf((float)l * inv) : cosf((float)l * inv);
    if (l < NLAYERS_)
        possig[idx] = (c < 512) ? sinf((float)l * inv) : cosf((float)l * inv);
}

// state += TIME_SIG[l,c] + POS_SIG[t,c]
__global__ __launch_bounds__(256) void add_sig_kernel(float* __restrict__ state,
                                                      const float* __restrict__ timesig,
                                                      const float* __restrict__ possig,
                                                      int layer_t) {
    int idx = blockIdx.x * 256 + threadIdx.x;
    int c = idx & (D_ - 1);
    int tl = idx & (L_ * D_ - 1);
    state[idx] += timesig[tl] + possig[layer_t * D_ + c];
}

// ---------------------------------------------------------------------------
__global__ __launch_bounds__(256) void act_kernel(const float* __restrict__ state,
                                                  const float* __restrict__ p_w,
                                                  const float* __restrict__ p_b,
                                                  float* __restrict__ hp, float* __restrict__ rem,
                                                  float* __restrict__ nup, float* __restrict__ uw) {
    int row = blockIdx.x;
    const float* x = state + (size_t)row * D_;
    float s = 0.f;
    for (int i = threadIdx.x; i < D_; i += 256) s += x[i] * p_w[i];
    __shared__ float red[256];
    red[threadIdx.x] = s; __syncthreads();
    for (int st = 128; st > 0; st >>= 1) {
        if (threadIdx.x < st) red[threadIdx.x] += red[threadIdx.x + st];
        __syncthreads();
    }
    if (threadIdx.x == 0) {
        float p = 1.f / (1.f + expf(-(red[0] + p_b[0])));
        float h = hp[row], r = rem[row], n = nup[row];
        float still = (h < 1.0f) ? 1.f : 0.f;
        float add = h + p * still;
        float nh     = (add > 0.9f) ? still : 0.f;
        float still2 = (add <= 0.9f) ? still : 0.f;
        h += p * still2;
        r += nh * (1.f - h);
        h += nh * r;
        n += still2 + nh;
        hp[row] = h; rem[row] = r; nup[row] = n;
        uw[row] = p * still2 + nh * r;
    }
}

// ---------------------------------------------------------------------------
// LayerNorm (ddof=1), fp32 in, split bf16 hi/lo out.  OUT_PAD: padded layout.
template<int OUT_PAD>
__global__ __launch_bounds__(256) void ln_kernel(const float* __restrict__ x,
                                                 const float* __restrict__ g,
                                                 const float* __restrict__ b,
                                                 ushort_t* __restrict__ yh,
                                                 ushort_t* __restrict__ yl) {
    int row = blockIdx.x;
    const float4* xr = (const float4*)(x + (size_t)row * D_);
    float4 v = xr[threadIdx.x];
    __shared__ float red[256];
    float s = v.x + v.y + v.z + v.w;
    red[threadIdx.x] = s; __syncthreads();
    for (int st = 128; st > 0; st >>= 1) { if (threadIdx.x < st) red[threadIdx.x] += red[threadIdx.x + st]; __syncthreads(); }
    float mu = red[0] * (1.f / D_);
    __syncthreads();
    float dx0 = v.x - mu, dx1 = v.y - mu, dx2 = v.z - mu, dx3 = v.w - mu;
    red[threadIdx.x] = dx0*dx0 + dx1*dx1 + dx2*dx2 + dx3*dx3; __syncthreads();
    for (int st = 128; st > 0; st >>= 1) { if (threadIdx.x < st) red[threadIdx.x] += red[threadIdx.x + st]; __syncthreads(); }
    float sd = sqrtf(red[0] * (1.f / (D_ - 1)));
    float inv = 1.f / (sd + 1e-6f);
    const float4* g4 = (const float4*)g;
    const float4* b4 = (const float4*)b;
    float4 gv = g4[threadIdx.x], bv = b4[threadIdx.x];
    float o0 = gv.x * dx0 * inv + bv.x;
    float o1 = gv.y * dx1 * inv + bv.y;
    float o2 = gv.z * dx2 * inv + bv.z;
    float o3 = gv.w * dx3 * inv + bv.w;
    int orow = OUT_PAD ? ((row >> 9) * LP_ + (row & (L_ - 1)) + 1) : row;
    ushort4 oh, ol;
    oh.x = f2bf(o0); ol.x = f2bf(o0 - bf2f(oh.x));
    oh.y = f2bf(o1); ol.y = f2bf(o1 - bf2f(oh.y));
    oh.z = f2bf(o2); ol.z = f2bf(o2 - bf2f(oh.z));
    oh.w = f2bf(o3); ol.w = f2bf(o3 - bf2f(oh.w));
    ((ushort4*)(yh + (size_t)orow * D_))[threadIdx.x] = oh;
    ((ushort4*)(yl + (size_t)orow * D_))[threadIdx.x] = ol;
}

// ---------------------------------------------------------------------------
// Transpose + split: dst[nbase+c][kbase+r] = split(scale * src[r][c])
__global__ __launch_bounds__(256) void transpose_split_kernel(const float* __restrict__ src,
                                                              ushort_t* __restrict__ dhi,
                                                              ushort_t* __restrict__ dlo,
                                                              int R, int C, int dstride,
                                                              int kbase, int nbase, float scale) {
    __shared__ float tile[32][33];
    int tx = threadIdx.x & 31, ty = threadIdx.x >> 5;   // 32 x 8
    int r0 = blockIdx.y * 32, c0 = blockIdx.x * 32;
#pragma unroll
    for (int i = 0; i < 4; ++i)
        tile[ty + i * 8][tx] = src[(size_t)(r0 + ty + i * 8) * C + c0 + tx] * scale;
    __syncthreads();
#pragma unroll
    for (int i = 0; i < 4; ++i) {
        int c = c0 + ty + i * 8;
        float val = tile[tx][ty + i * 8];
        ushort_t hi = f2bf(val);
        ushort_t lo = f2bf(val - bf2f(hi));
        size_t idx = (size_t)(nbase + c) * dstride + kbase + r0 + tx;
        dhi[idx] = hi; dlo[idx] = lo;
    }
}

// ---------------------------------------------------------------------------
// Zero halo rows of all four padded activation buffers
__global__ __launch_bounds__(256) void zero_halo_kernel(ushort_t* __restrict__ xh,
                                                        ushort_t* __restrict__ xl,
                                                        ushort_t* __restrict__ hh,
                                                        ushort_t* __restrict__ hl) {
    int idx = blockIdx.x * 256 + threadIdx.x;          // 81920 total
    if (idx < 16384) {
        int b = idx >> 11, r = (idx >> 10) & 1, c = idx & 1023;
        size_t o = ((size_t)b * LP_ + r * (LP_ - 1)) * D_ + c;
        xh[o] = 0; xl[o] = 0;
    } else {
        int j = idx - 16384;
        int b = j >> 13, r = (j >> 12) & 1, c = j & 4095;
        size_t o = ((size_t)b * LP_ + r * (LP_ - 1)) * FILT_ + c;
        hh[o] = 0; hl[o] = 0;
    }
}

// ---------------------------------------------------------------------------
// bf16x3 MFMA GEMM: C = epi( A @ Bt^T ), A ~ Ahi+Alo, B ~ Bhi+Blo.
// 128(M) x 64(N) block tile, BK=64; 4 waves in 2x2, each 64m x 32n
// (4x2 of 16x16x32 MFMA, 3 passes).  LDS 48 KB -> 3 blocks/CU.
// GROUP_M=8 swizzle: consecutive blocks share the B n-band (L2 locality).
// PAD: A is im2col view of padded (B, LP_, Din).  OUT_MODE: 0=f32 store,
// 1=f32 accumulate, 3=split bf16 store padded.
template<int PAD, int DIN_SHIFT, int OUT_MODE, int RELU, int HAS_BIAS>
__global__ __launch_bounds__(256, 3) void mfma_gemm(const ushort_t* __restrict__ Ahi,
                                                    const ushort_t* __restrict__ Alo,
                                                    const ushort_t* __restrict__ Bhi,
                                                    const ushort_t* __restrict__ Blo,
                                                    void* __restrict__ C,
                                                    ushort_t* __restrict__ Clo,
                                                    const float* __restrict__ bias,
                                                    int M, int N, int K) {
    __shared__ __align__(16) ushort_t AsH[128 * 64];
    __shared__ __align__(16) ushort_t AsL[128 * 64];
    __shared__ __align__(16) ushort_t BsH[64 * 64];
    __shared__ __align__(16) ushort_t BsL[64 * 64];
    int tid = threadIdx.x;
    int w = tid >> 6, l = tid & 63;
    // GROUP_M=8 swizzle (gridDim.y multiple of 8)
    int bid = blockIdx.y * gridDim.x + blockIdx.x;
    int stripe = 8 * gridDim.x;
    int m0 = ((bid / stripe) * 8 + (bid & 7)) * 128;
    int n0 = ((bid % stripe) >> 3) * 64;
    int wm = (w >> 1) * 64, wn = (w & 1) * 32;

    f32x4 acc[4][2];
#pragma unroll
    for (int i = 0; i < 4; ++i)
#pragma unroll
        for (int j = 0; j < 2; ++j) acc[i][j] = (f32x4)0.f;

    for (int k0 = 0; k0 < K; k0 += 64) {
        int tap = 0, c0 = 0;
        if (PAD) { tap = k0 >> DIN_SHIFT; c0 = k0 & ((1 << DIN_SHIFT) - 1); }
        // ---- stage A tile (128 rows x 64 k): 1024 chunks, 4 issues/thread
#pragma unroll
        for (int i = 0; i < 4; ++i) {
            int q = i * 256 + tid;
            int r = q >> 3;
            int cs = (q & 7) ^ (r & 7);
            size_t goffA;
            if (PAD) {
                int row = m0 + r;
                int rg = (row >> 9) * LP_ + (row & (L_ - 1)) + tap;
                goffA = ((size_t)rg << DIN_SHIFT) + c0 + cs * 8;
            } else {
                goffA = (size_t)(m0 + r) * K + k0 + cs * 8;
            }
            size_t lbase = (size_t)(i * 256 + w * 64) * 8;
            GLOAD_LDS16(Ahi + goffA, AsH + lbase);
            GLOAD_LDS16(Alo + goffA, AsL + lbase);
        }
        // ---- stage B tile (64 n-rows x 64 k): 512 chunks, 2 issues/thread
#pragma unroll
        for (int i = 0; i < 2; ++i) {
            int q = i * 256 + tid;
            int r = q >> 3;
            int cs = (q & 7) ^ (r & 7);
            size_t goffB = (size_t)(n0 + r) * K + k0 + cs * 8;
            size_t lbase = (size_t)(i * 256 + w * 64) * 8;
            GLOAD_LDS16(Bhi + goffB, BsH + lbase);
            GLOAD_LDS16(Blo + goffB, BsL + lbase);
        }
        __syncthreads();
#pragma unroll
        for (int ks = 0; ks < 2; ++ks) {
            short8 afh[4], afl[4], bfh[2], bfl[2];
#pragma unroll
            for (int t = 0; t < 4; ++t) {
                int rA = wm + t * 16 + (l & 15);
                int cA = (ks * 4 + (l >> 4)) ^ (rA & 7);
                afh[t] = *(const short8*)(AsH + ((size_t)rA * 8 + cA) * 8);
                afl[t] = *(const short8*)(AsL + ((size_t)rA * 8 + cA) * 8);
            }
#pragma unroll
            for (int t = 0; t < 2; ++t) {
                int rB = wn + t * 16 + (l & 15);
                int cB = (ks * 4 + (l >> 4)) ^ (rB & 7);
                bfh[t] = *(const short8*)(BsH + ((size_t)rB * 8 + cB) * 8);
                bfl[t] = *(const short8*)(BsL + ((size_t)rB * 8 + cB) * 8);
            }
#pragma unroll
            for (int i = 0; i < 4; ++i)
#pragma unroll
                for (int j = 0; j < 2; ++j) {
                    acc[i][j] = __builtin_amdgcn_mfma_f32_16x16x32_bf16(afh[i], bfh[j], acc[i][j], 0, 0, 0);
                    acc[i][j] = __builtin_amdgcn_mfma_f32_16x16x32_bf16(afl[i], bfh[j], acc[i][j], 0, 0, 0);
                    acc[i][j] = __builtin_amdgcn_mfma_f32_16x16x32_bf16(afh[i], bfl[j], acc[i][j], 0, 0, 0);
                }
        }
        __syncthreads();
    }
    // epilogue.  C/D layout: col = lane&15, row = (lane>>4)*4 + reg
#pragma unroll
    for (int i = 0; i < 4; ++i) {
#pragma unroll
        for (int j = 0; j < 2; ++j) {
#pragma unroll
            for (int r = 0; r < 4; ++r) {
                int row = m0 + wm + i * 16 + (l >> 4) * 4 + r;
                int col = n0 + wn + j * 16 + (l & 15);
                float v = acc[i][j][r];
                if (HAS_BIAS) v += bias[col];
                if (RELU) v = fmaxf(v, 0.f);
                size_t off;
                if (OUT_MODE == 3) off = (size_t)((row >> 9) * LP_ + (row & (L_ - 1)) + 1) * N + col;
                else               off = (size_t)row * N + col;
                if (OUT_MODE == 0) {
                    ((float*)C)[off] = v;
                } else if (OUT_MODE == 1) {
                    float* Cf = (float*)C;
                    Cf[off] += v;
                } else {
                    ushort_t hi = f2bf(v);
                    ((ushort_t*)C)[off] = hi;
                    Clo[off] = f2bf(v - bf2f(hi));
                }
            }
        }
    }
}

// ---------------------------------------------------------------------------
// V transpose+split: Vt[b,h,d,key] (hi/lo bf16) from qkv fp32 V-section.
__global__ __launch_bounds__(256) void vt_kernel(const float* __restrict__ qkv,
                                                 ushort_t* __restrict__ Vth,
                                                 ushort_t* __restrict__ Vtl) {
    __shared__ float t[64][65];
    int kt = blockIdx.x, h = blockIdx.y, b = blockIdx.z;
    int tx = threadIdx.x & 63, ty = threadIdx.x >> 6;  // 64 x 4
#pragma unroll
    for (int i = 0; i < 16; ++i) {
        int r = ty + i * 4;            // key within tile
        t[r][tx] = qkv[(size_t)(b * L_ + kt * 64 + r) * (3 * D_) + 2 * D_ + h * DKH_ + tx];
    }
    __syncthreads();
#pragma unroll
    for (int i = 0; i < 16; ++i) {
        int d = ty + i * 4;
        float v = t[tx][d];            // key=tx, dim=d
        size_t o = ((size_t)((b * H_ + h) * DKH_ + d)) * L_ + kt * 64 + tx;
        ushort_t hj = f2bf(v);
        Vth[o] = hj; Vtl[o] = f2bf(v - bf2f(hj));
    }
}

// ---------------------------------------------------------------------------
// Flash MFMA attention, bf16x3 split precision (~fp32), online softmax.
__global__ __launch_bounds__(256, 2) void fattn_kernel(const float* __restrict__ qkv,
                                                       const ushort_t* __restrict__ Vth,
                                                       const ushort_t* __restrict__ Vtl,
                                                       ushort_t* __restrict__ ctxh,
                                                       ushort_t* __restrict__ ctxl) {
    __shared__ __align__(16) ushort_t Ph[4][32 * 136];
    __shared__ __align__(16) ushort_t Pl[4][32 * 136];
    int qt = blockIdx.x, h = blockIdx.y, b = blockIdx.z;
    int w = threadIdx.x >> 6, l = threadIdx.x & 63;
    int lm = l & 15, lq = l >> 4;
    int q0 = qt * 128 + w * 32;

    short8 qfh[2][2], qfl[2][2];
#pragma unroll
    for (int mt = 0; mt < 2; ++mt)
#pragma unroll
        for (int ks = 0; ks < 2; ++ks) {
            const float* qp = qkv + (size_t)(b * L_ + q0 + mt * 16 + lm) * (3 * D_)
                              + h * DKH_ + ks * 32 + lq * 8;
            short8 hi, lo;
#pragma unroll
            for (int j = 0; j < 8; ++j) {
                float x = qp[j];
                ushort_t hj = f2bf(x);
                hi[j] = (short)hj;
                lo[j] = (short)f2bf(x - bf2f(hj));
            }
            qfh[mt][ks] = hi; qfl[mt][ks] = lo;
        }

    float mrow[2][4], lrow[2][4];
    f32x4 oacc[2][4];
#pragma unroll
    for (int mt = 0; mt < 2; ++mt)
#pragma unroll
        for (int r = 0; r < 4; ++r) { mrow[mt][r] = -3.0e38f; lrow[mt][r] = 0.f; }
#pragma unroll
    for (int mt = 0; mt < 2; ++mt)
#pragma unroll
        for (int nt = 0; nt < 4; ++nt) oacc[mt][nt] = (f32x4)0.f;

    for (int c = 0; c < 4; ++c) {           // key chunks of 128
        f32x4 s[2][8];
#pragma unroll
        for (int mt = 0; mt < 2; ++mt)
#pragma unroll
            for (int nt = 0; nt < 8; ++nt) s[mt][nt] = (f32x4)0.f;

#pragma unroll
        for (int nt = 0; nt < 8; ++nt) {
#pragma unroll
            for (int ks = 0; ks < 2; ++ks) {
                const float* kp = qkv + (size_t)(b * L_ + c * 128 + nt * 16 + lm) * (3 * D_)
                                  + D_ + h * DKH_ + ks * 32 + lq * 8;
                short8 kh, kl;
#pragma unroll
                for (int j = 0; j < 8; ++j) {
                    float x = kp[j];
                    ushort_t hj = f2bf(x);
                    kh[j] = (short)hj;
                    kl[j] = (short)f2bf(x - bf2f(hj));
                }
#pragma unroll
                for (int mt = 0; mt < 2; ++mt) {
                    s[mt][nt] = __builtin_amdgcn_mfma_f32_16x16x32_bf16(qfh[mt][ks], kh, s[mt][nt], 0, 0, 0);
                    s[mt][nt] = __builtin_amdgcn_mfma_f32_16x16x32_bf16(qfl[mt][ks], kh, s[mt][nt], 0, 0, 0);
                    s[mt][nt] = __builtin_amdgcn_mfma_f32_16x16x32_bf16(qfh[mt][ks], kl, s[mt][nt], 0, 0, 0);
                }
            }
        }

#pragma unroll
        for (int mt = 0; mt < 2; ++mt) {
#pragma unroll
            for (int r = 0; r < 4; ++r) {
                float cm = s[mt][0][r];
#pragma unroll
                for (int nt = 1; nt < 8; ++nt) cm = fmaxf(cm, s[mt][nt][r]);
                cm = fmaxf(cm, __shfl_xor(cm, 1));
                cm = fmaxf(cm, __shfl_xor(cm, 2));
                cm = fmaxf(cm, __shfl_xor(cm, 4));
                cm = fmaxf(cm, __shfl_xor(cm, 8));
                float mnew = fmaxf(mrow[mt][r], cm);
                float alpha = expf(mrow[mt][r] - mnew);
                mrow[mt][r] = mnew;
                float ps = 0.f;
                int rw = mt * 16 + lq * 4 + r;
#pragma unroll
                for (int nt = 0; nt < 8; ++nt) {
                    float p = expf(s[mt][nt][r] - mnew);
                    ps += p;
                    ushort_t hj = f2bf(p);
                    int cl = nt * 16 + lm;
                    Ph[w][rw * 136 + cl] = hj;
                    Pl[w][rw * 136 + cl] = f2bf(p - bf2f(hj));
                }
                ps += __shfl_xor(ps, 1);
                ps += __shfl_xor(ps, 2);
                ps += __shfl_xor(ps, 4);
                ps += __shfl_xor(ps, 8);
                lrow[mt][r] = lrow[mt][r] * alpha + ps;
#pragma unroll
                for (int nt = 0; nt < 4; ++nt) oacc[mt][nt][r] *= alpha;
            }
        }
        asm volatile("s_waitcnt lgkmcnt(0)" ::: "memory");

#pragma unroll
        for (int ks = 0; ks < 4; ++ks) {
            short8 pah[2], pal[2];
#pragma unroll
            for (int mt = 0; mt < 2; ++mt) {
                pah[mt] = *(const short8*)&Ph[w][(mt * 16 + lm) * 136 + ks * 32 + lq * 8];
                pal[mt] = *(const short8*)&Pl[w][(mt * 16 + lm) * 136 + ks * 32 + lq * 8];
            }
#pragma unroll
            for (int nt = 0; nt < 4; ++nt) {
                size_t vo = ((size_t)((b * H_ + h) * DKH_ + nt * 16 + lm)) * L_ + c * 128 + ks * 32 + lq * 8;
                short8 vh = *(const short8*)(Vth + vo);
                short8 vl = *(const short8*)(Vtl + vo);
#pragma unroll
                for (int mt = 0; mt < 2; ++mt) {
                    oacc[mt][nt] = __builtin_amdgcn_mfma_f32_16x16x32_bf16(pah[mt], vh, oacc[mt][nt], 0, 0, 0);
                    oacc[mt][nt] = __builtin_amdgcn_mfma_f32_16x16x32_bf16(pal[mt], vh, oacc[mt][nt], 0, 0, 0);
                    oacc[mt][nt] = __builtin_amdgcn_mfma_f32_16x16x32_bf16(pah[mt], vl, oacc[mt][nt], 0, 0, 0);
                }
            }
        }
        asm volatile("s_waitcnt lgkmcnt(0)" ::: "memory");
    }

#pragma unroll
    for (int mt = 0; mt < 2; ++mt) {
#pragma unroll
        for (int nt = 0; nt < 4; ++nt) {
#pragma unroll
            for (int r = 0; r < 4; ++r) {
                float v = oacc[mt][nt][r] / lrow[mt][r];
                int rowg = b * L_ + qt * 128 + w * 32 + mt * 16 + lq * 4 + r;
                int colg = h * DKH_ + nt * 16 + lm;
                size_t o = (size_t)rowg * D_ + colg;
                ushort_t hj = f2bf(v);
                ctxh[o] = hj;
                ctxl[o] = f2bf(v - bf2f(hj));
            }
        }
    }
}

// ---------------------------------------------------------------------------
__global__ __launch_bounds__(256) void prev_kernel(const float* __restrict__ state,
                                                   float* __restrict__ prev,
                                                   const float* __restrict__ uw) {
    int idx = blockIdx.x * 256 + threadIdx.x;
    int row = idx >> 10;
    float u = uw[row];
    prev[idx] = state[idx] * u + prev[idx] * (1.f - u);
}

// ---------------------------------------------------------------------------
__global__ __launch_bounds__(256) void mean_kernel(const float* __restrict__ prev,
                                                   float* __restrict__ meanbuf) {
    int idx = blockIdx.x * 256 + threadIdx.x;  // 8192
    int b = idx >> 10, d = idx & (D_ - 1);
    float s = 0.f;
    for (int l = 0; l < L_; ++l) s += prev[((size_t)(b * L_ + l) << 10) + d];
    meanbuf[idx] = s * (1.f / L_);
}

// ---------------------------------------------------------------------------
__global__ __launch_bounds__(256) void final_kernel(const float* __restrict__ meanbuf,
                                                    const float* __restrict__ W_out,
                                                    const float* __restrict__ b_out,
                                                    const float* __restrict__ rem,
                                                    const float* __restrict__ nup,
                                                    float* __restrict__ out) {
    int tid = threadIdx.x;
    int grp = tid >> 3;
    int lane = tid & 7;
    int b = grp >> 2, j = grp & 3;
    float s = 0.f;
    for (int d2 = lane; d2 < D_; d2 += 8) s += meanbuf[b * D_ + d2] * W_out[d2 * 4 + j];
    for (int st = 4; st >= 1; st >>= 1) s += __shfl_down(s, st, 8);
    __shared__ float ah[32];
    if (lane == 0) ah[grp] = s + b_out[j];
    __syncthreads();
    if (tid < 8) {
        float a0 = ah[tid * 4 + 0], a1 = ah[tid * 4 + 1], a2 = ah[tid * 4 + 2], a3 = ah[tid * 4 + 3];
        out[tid * 4 + 0] = a0; out[tid * 4 + 1] = a1; out[tid * 4 + 2] = a2; out[tid * 4 + 3] = a3;
        float mx = fmaxf(fmaxf(a0, a1), fmaxf(a2, a3));
        float e0 = expf(a0 - mx), e1 = expf(a1 - mx), e2 = expf(a2 - mx), e3 = expf(a3 - mx);
        float sm = e0 + e1 + e2 + e3;
        out[32 + tid * 4 + 0] = e0 / sm; out[32 + tid * 4 + 1] = e1 / sm;
        out[32 + tid * 4 + 2] = e2 / sm; out[32 + tid * 4 + 3] = e3 / sm;
    }
    for (int i = tid; i < ROWS_; i += 256) {
        out[64 + i] = rem[i];
        out[64 + ROWS_ + i] = nup[i];
    }
}

// ---------------------------------------------------------------------------
extern "C" void kernel_launch(void* const* d_in, const int* in_sizes, int n_in,
                              void* d_out, int out_size, void* d_ws, size_t ws_size,
                              hipStream_t stream) {
    const int*   X     = (const int*)  d_in[0];
    const float* emb   = (const float*)d_in[1];
    const float* p_w   = (const float*)d_in[2];
    const float* p_b   = (const float*)d_in[3];
    const float* Wq    = (const float*)d_in[4];
    const float* Wk    = (const float*)d_in[5];
    const float* Wv    = (const float*)d_in[6];
    const float* Wo    = (const float*)d_in[7];
    const float* ln1_g = (const float*)d_in[8];
    const float* ln1_b = (const float*)d_in[9];
    const float* ln2_g = (const float*)d_in[10];
    const float* ln2_b = (const float*)d_in[11];
    const float* K1    = (const float*)d_in[12];
    const float* c1_b  = (const float*)d_in[13];
    const float* K2    = (const float*)d_in[14];
    const float* c2_b  = (const float*)d_in[15];
    const float* W_out = (const float*)d_in[16];
    const float* b_out = (const float*)d_in[17];

    char* ws = (char*)d_ws;
    size_t off = 0;
    auto alloc = [&](size_t bytes) { char* p = ws + off; off += (bytes + 255) & ~(size_t)255; return p; };

    float*    state  = (float*)alloc(NE_ * 4);
    float*    prev   = (float*)alloc(NE_ * 4);
    ushort_t* xn1h   = (ushort_t*)alloc(NE_ * 2);
    ushort_t* xn1l   = (ushort_t*)alloc(NE_ * 2);
    ushort_t* ctxh   = (ushort_t*)alloc(NE_ * 2);
    ushort_t* ctxl   = (ushort_t*)alloc(NE_ * 2);
    ushort_t* xn2ph  = (ushort_t*)alloc((size_t)B_ * LP_ * D_ * 2);
    ushort_t* xn2pl  = (ushort_t*)alloc((size_t)B_ * LP_ * D_ * 2);
    // union region (67.37 MB): [ qkv fp32 50.33 MB | Vth 8.39 | Vtl 8.39 ]
    // later aliased by h_hi|h_lo padded conv buffers
    char*     uni    = alloc((size_t)B_ * LP_ * FILT_ * 2 * 2);
    float*    qkv    = (float*)uni;
    ushort_t* Vth    = (ushort_t*)(uni + (size_t)ROWS_ * 3 * D_ * 4);
    ushort_t* Vtl    = Vth + (size_t)B_ * H_ * DKH_ * L_;
    ushort_t* hbh    = (ushort_t*)uni;
    ushort_t* hbl    = (ushort_t*)(uni + (size_t)B_ * LP_ * FILT_ * 2);
    ushort_t* WqkvTh = (ushort_t*)alloc((size_t)(3 * D_) * D_ * 2);
    ushort_t* WqkvTl = (ushort_t*)alloc((size_t)(3 * D_) * D_ * 2);
    ushort_t* WoTh   = (ushort_t*)alloc((size_t)D_ * D_ * 2);
    ushort_t* WoTl   = (ushort_t*)alloc((size_t)D_ * D_ * 2);
    ushort_t* K1Th   = (ushort_t*)alloc((size_t)FILT_ * (3 * D_) * 2);
    ushort_t* K1Tl   = (ushort_t*)alloc((size_t)FILT_ * (3 * D_) * 2);
    ushort_t* K2Th   = (ushort_t*)alloc((size_t)D_ * (3 * FILT_) * 2);
    ushort_t* K2Tl   = (ushort_t*)alloc((size_t)D_ * (3 * FILT_) * 2);
    float* timesig = (float*)alloc((size_t)L_ * D_ * 4);
    float* possig  = (float*)alloc((size_t)NLAYERS_ * D_ * 4);
    float* hp      = (float*)alloc(ROWS_ * 4);
    float* rem     = (float*)alloc(ROWS_ * 4);
    float* nup     = (float*)alloc(ROWS_ * 4);
    float* uw      = (float*)alloc(ROWS_ * 4);
    float* meanbuf = (float*)alloc(B_ * D_ * 4);

    hipMemsetAsync(prev, 0, NE_ * 4, stream);
    hipMemsetAsync(hp, 0, ROWS_ * 4, stream);
    hipMemsetAsync(rem, 0, ROWS_ * 4, stream);
    hipMemsetAsync(nup, 0, ROWS_ * 4, stream);

    // weight prep: transpose + split; fold q-scale 0.125 (exact pow2) into Wq
    transpose_split_kernel<<<dim3(32, 32), 256, 0, stream>>>(Wq, WqkvTh, WqkvTl, D_, D_, D_, 0, 0,       0.125f);
    transpose_split_kernel<<<dim3(32, 32), 256, 0, stream>>>(Wk, WqkvTh, WqkvTl, D_, D_, D_, 0, D_,      1.f);
    transpose_split_kernel<<<dim3(32, 32), 256, 0, stream>>>(Wv, WqkvTh, WqkvTl, D_, D_, D_, 0, 2 * D_,  1.f);
    transpose_split_kernel<<<dim3(32, 32), 256, 0, stream>>>(Wo, WoTh, WoTl, D_, D_, D_, 0, 0, 1.f);
    for (int t = 0; t < 3; ++t) {
        transpose_split_kernel<<<dim3(128, 32), 256, 0, stream>>>(
            K1 + (size_t)t * D_ * FILT_, K1Th, K1Tl, D_, FILT_, 3 * D_, t * D_, 0, 1.f);
        transpose_split_kernel<<<dim3(32, 128), 256, 0, stream>>>(
            K2 + (size_t)t * FILT_ * D_, K2Th, K2Tl, FILT_, D_, 3 * FILT_, t * FILT_, 0, 1.f);
    }
    sig_kernel<<<(L_ * D_) / 256, 256, 0, stream>>>(timesig, possig);

    embed_kernel<<<ROWS_, 256, 0, stream>>>(X, emb, state);

    dim3 gQKV(3 * D_ / 64, ROWS_ / 128);   // (48, 32)
    dim3 gWo(D_ / 64, ROWS_ / 128);        // (16, 32)
    dim3 gC1(FILT_ / 64, ROWS_ / 128);     // (64, 32)

    for (int t = 0; t < NLAYERS_; ++t) {
        add_sig_kernel<<<NE_ / 256, 256, 0, stream>>>(state, timesig, possig, t);
        act_kernel<<<ROWS_, 256, 0, stream>>>(state, p_w, p_b, hp, rem, nup, uw);
        ln_kernel<0><<<ROWS_, 256, 0, stream>>>(state, ln1_g, ln1_b, xn1h, xn1l);

        // qkv = xn @ [0.125*Wq | Wk | Wv]  (fp32 out)
        mfma_gemm<0,0,0,0,0><<<gQKV, 256, 0, stream>>>(xn1h, xn1l, WqkvTh, WqkvTl,
                                                       qkv, nullptr, nullptr, ROWS_, 3 * D_, D_);
        vt_kernel<<<dim3(L_ / 64, H_, B_), 256, 0, stream>>>(qkv, Vth, Vtl);
        fattn_kernel<<<dim3(L_ / 128, H_, B_), 256, 0, stream>>>(qkv, Vth, Vtl, ctxh, ctxl);

        // state += ctx @ Wo
        mfma_gemm<0,0,1,0,0><<<gWo, 256, 0, stream>>>(ctxh, ctxl, WoTh, WoTl,
                                                      state, nullptr, nullptr, ROWS_, D_, D_);

        // re-zero conv halos (h region aliases qkv/Vt — now dead)
        zero_halo_kernel<<<81920 / 256, 256, 0, stream>>>(xn2ph, xn2pl, hbh, hbl);

        ln_kernel<1><<<ROWS_, 256, 0, stream>>>(state, ln2_g, ln2_b, xn2ph, xn2pl);

        // h = relu(conv1(xn2) + c1_b)  -> padded split bf16
        mfma_gemm<1,10,3,1,1><<<gC1, 256, 0, stream>>>(xn2ph, xn2pl, K1Th, K1Tl,
                                                       hbh, hbl, c1_b, ROWS_, FILT_, 3 * D_);
        // state += conv2(h) + c2_b
        mfma_gemm<1,12,1,0,1><<<gWo, 256, 0, stream>>>(hbh, hbl, K2Th, K2Tl,
                                                       state, nullptr, c2_b, ROWS_, D_, 3 * FILT_);

        prev_kernel<<<NE_ / 256, 256, 0, stream>>>(state, prev, uw);
    }

    mean_kernel<<<(B_ * D_) / 256, 256, 0, stream>>>(prev, meanbuf);
    final_kernel<<<1, 256, 0, stream>>>(meanbuf, W_out, b_out, rem, nup, (float*)d_out);
}